// Round 3
// baseline (545.672 us; speedup 1.0000x reference)
//
#include <hip/hip_runtime.h>

// MultiHeadedAttention: B=4, S=2048, H=16, D_MODEL=1024, D_K=64
// Softmax over the QUERY axis (per key-column normalization).
// Pipeline: wprep -> proj_gemm(QKV) -> colsum -> vscale -> attnpv -> out_gemm
// R2: attnpv/colsum restructured around transposed scores (S^T = K.Q^T):
//     - exp results pack to ds_write_b64 (was 32x scalar ds_write_b16)
//     - K/V/Q frags load global->VGPR directly (no LDS staging, L2/L3-resident)
//     - attnpv: LDS = Ps only (18.4KB), 2 barriers/iter (was 3), K/V prefetch
//     - colsum: zero LDS, zero barriers, shfl reduction

#define DEV __device__ __forceinline__

typedef __bf16 bf16x8 __attribute__((ext_vector_type(8)));
typedef float  f32x4  __attribute__((ext_vector_type(4)));

DEV unsigned short f2bf(float f) {
    __bf16 h = (__bf16)f;
    return __builtin_bit_cast(unsigned short, h);
}

DEV bf16x8 ldfrag(const unsigned short* p) {
    return *reinterpret_cast<const bf16x8*>(p);
}

DEV float fast_exp2(float x) {
#if __has_builtin(__builtin_amdgcn_exp2f)
    return __builtin_amdgcn_exp2f(x);
#else
    return exp2f(x);
#endif
}

DEV void cvt8_store(unsigned short* dst, float4 a, float4 b) {
    bf16x8 v;
    v[0]=(__bf16)a.x; v[1]=(__bf16)a.y; v[2]=(__bf16)a.z; v[3]=(__bf16)a.w;
    v[4]=(__bf16)b.x; v[5]=(__bf16)b.y; v[6]=(__bf16)b.z; v[7]=(__bf16)b.w;
    *reinterpret_cast<bf16x8*>(dst) = v;
}

#define MFMA(a,b,c) __builtin_amdgcn_mfma_f32_16x16x32_bf16((a),(b),(c),0,0,0)

// score*1/sqrt(64) then exp -> exp2(score * log2(e)/8); folded into Qh.
#define QSCALE 0.18033688011112042f

// ---------------------------------------------------------------------------
// Weight prep: Wq/Wk/Wv [16,1024,64] f32 -> Wt[z][n=h*64+k][m] bf16 (B^T layout)
//              Wo [1024,1024] f32 -> bf16 (already [n][m])
// ---------------------------------------------------------------------------
__global__ __launch_bounds__(256) void wprep(const float* __restrict__ Wq,
                                             const float* __restrict__ Wk,
                                             const float* __restrict__ Wv,
                                             const float* __restrict__ Wo,
                                             unsigned short* __restrict__ Wt,
                                             unsigned short* __restrict__ Wot) {
    int idx = blockIdx.x * 256 + threadIdx.x;   // < 1024*1024
    int which = blockIdx.y;
    if (which == 3) { Wot[idx] = f2bf(Wo[idx]); return; }
    const float* W = (which == 0) ? Wq : (which == 1) ? Wk : Wv;
    int n = idx >> 10, m = idx & 1023;
    int h = n >> 6, k = n & 63;
    Wt[(size_t)which * 1048576 + idx] = f2bf(W[h * 65536 + m * 64 + k]);
}

// ---------------------------------------------------------------------------
// Projection GEMM: C[8192 x 1024] = X(f32->bf16) * Wt^T + bias
// z=0 -> Qh[b,h,s,k] bf16, pre-scaled by QSCALE ; z=1 -> Kh[b,h,s,k]
// z=2 -> Vt[b,h,k,s] (transposed)
// ---------------------------------------------------------------------------
__global__ __launch_bounds__(256) void proj_gemm(
        const float* __restrict__ Xq, const float* __restrict__ Xk,
        const float* __restrict__ Xv, const unsigned short* __restrict__ Wt,
        const float* __restrict__ bq, const float* __restrict__ bk,
        const float* __restrict__ bv,
        unsigned short* __restrict__ Qh, unsigned short* __restrict__ Kh,
        unsigned short* __restrict__ Vt) {
    const int tid = threadIdx.x;
    const int bm = blockIdx.x, bn = blockIdx.y, z = blockIdx.z;
    const float* X = (z == 0) ? Xq : (z == 1) ? Xk : Xv;
    const unsigned short* Bt = Wt + (size_t)z * 1048576;
    const float* bias = (z == 0) ? bq : (z == 1) ? bk : bv;

    __shared__ __align__(16) unsigned short As[128 * 40];
    __shared__ __align__(16) unsigned short Bs[128 * 40];

    const int lane = tid & 63, wid = tid >> 6;
    const int l16 = lane & 15, quad = lane >> 4;
    const int wm = wid & 1, wn = wid >> 1;

    f32x4 acc[4][4] = {};

    for (int kt = 0; kt < 32; ++kt) {
        __syncthreads();
        const int k0 = kt * 32;
#pragma unroll
        for (int i = 0; i < 2; ++i) {
            int seg = tid + i * 256;          // 512 segs of 8 elems
            int row = seg >> 2, s4 = seg & 3;
            const float* gp = X + (size_t)(bm * 128 + row) * 1024 + k0 + s4 * 8;
            float4 f0 = *(const float4*)gp;
            float4 f1 = *(const float4*)(gp + 4);
            cvt8_store(&As[row * 40 + s4 * 8], f0, f1);
            const unsigned short* bp = Bt + (size_t)(bn * 128 + row) * 1024 + k0 + s4 * 8;
            *(uint4*)&Bs[row * 40 + s4 * 8] = *(const uint4*)bp;
        }
        __syncthreads();
        bf16x8 af[4], bfr[4];
#pragma unroll
        for (int mi = 0; mi < 4; ++mi)
            af[mi] = ldfrag(&As[(wm * 64 + mi * 16 + l16) * 40 + quad * 8]);
#pragma unroll
        for (int ni = 0; ni < 4; ++ni)
            bfr[ni] = ldfrag(&Bs[(wn * 64 + ni * 16 + l16) * 40 + quad * 8]);
#pragma unroll
        for (int mi = 0; mi < 4; ++mi)
#pragma unroll
            for (int ni = 0; ni < 4; ++ni)
                acc[mi][ni] = MFMA(af[mi], bfr[ni], acc[mi][ni]);
    }

#pragma unroll
    for (int mi = 0; mi < 4; ++mi)
#pragma unroll
        for (int ni = 0; ni < 4; ++ni)
#pragma unroll
            for (int r = 0; r < 4; ++r) {
                int row = bm * 128 + wm * 64 + mi * 16 + quad * 4 + r;  // flat b*s
                int col = bn * 128 + wn * 64 + ni * 16 + l16;           // h*64+k
                float v = acc[mi][ni][r] + bias[col];
                if (z == 0) v *= QSCALE;
                int b = row >> 11, s = row & 2047;
                int h = col >> 6, k = col & 63;
                unsigned short o = f2bf(v);
                if (z == 2) {
                    Vt[(size_t)((b * 16 + h) * 64 + k) * 2048 + s] = o;
                } else {
                    unsigned short* O = (z == 0) ? Qh : Kh;
                    O[(size_t)((b * 16 + h) * 2048 + s) * 64 + k] = o;
                }
            }
}

// ---------------------------------------------------------------------------
// Column softmax denominators: Dcol[b,h,s] = sum_q exp2(S^T[s,q])
// S^T = K.Q^T : A-frags = K (register resident), B-frags = Q (global->reg).
// No LDS, no barriers. Each wave owns 32 s rows, sums over all 2048 q.
// ---------------------------------------------------------------------------
__global__ __launch_bounds__(256) void colsum(const unsigned short* __restrict__ Qh,
                                              const unsigned short* __restrict__ Kh,
                                              float* __restrict__ Dcol) {
    const int tid = threadIdx.x;
    const int st = blockIdx.x, bh = blockIdx.y;
    const unsigned short* Qb = Qh + (size_t)bh * 2048 * 64;
    const unsigned short* Kb = Kh + (size_t)bh * 2048 * 64;

    const int lane = tid & 63, wid = tid >> 6;
    const int l16 = lane & 15, quad = lane >> 4;

    // K A-frags for this wave's 32 s rows, register resident
    bf16x8 kf[2][2];
#pragma unroll
    for (int mi = 0; mi < 2; ++mi)
#pragma unroll
        for (int ks = 0; ks < 2; ++ks)
            kf[mi][ks] = ldfrag(&Kb[(size_t)(st * 128 + wid * 32 + mi * 16 + l16) * 64 +
                                    ks * 32 + quad * 8]);

    float psum[2][4] = {};
    const unsigned short* qp = Qb + (size_t)l16 * 64 + quad * 8;
    for (int q0 = 0; q0 < 2048; q0 += 64) {
        bf16x8 qf[2][4];
#pragma unroll
        for (int nj = 0; nj < 4; ++nj)
#pragma unroll
            for (int ks = 0; ks < 2; ++ks)
                qf[ks][nj] = ldfrag(qp + (size_t)(q0 + nj * 16) * 64 + ks * 32);
        f32x4 acc[2][4] = {};
#pragma unroll
        for (int ks = 0; ks < 2; ++ks)
#pragma unroll
            for (int mi = 0; mi < 2; ++mi)
#pragma unroll
                for (int nj = 0; nj < 4; ++nj)
                    acc[mi][nj] = MFMA(kf[mi][ks], qf[ks][nj], acc[mi][nj]);
#pragma unroll
        for (int mi = 0; mi < 2; ++mi)
#pragma unroll
            for (int nj = 0; nj < 4; ++nj)
#pragma unroll
                for (int r = 0; r < 4; ++r)
                    psum[mi][r] += fast_exp2(acc[mi][nj][r]);
    }
    // reduce over the 16 l16-lanes (q columns held per lane group)
#pragma unroll
    for (int mi = 0; mi < 2; ++mi)
#pragma unroll
        for (int r = 0; r < 4; ++r) {
            float v = psum[mi][r];
            v += __shfl_xor(v, 1, 64);
            v += __shfl_xor(v, 2, 64);
            v += __shfl_xor(v, 4, 64);
            v += __shfl_xor(v, 8, 64);
            psum[mi][r] = v;
        }
    if (l16 == 0) {
#pragma unroll
        for (int mi = 0; mi < 2; ++mi)
#pragma unroll
            for (int r = 0; r < 4; ++r)
                Dcol[(size_t)bh * 2048 + st * 128 + wid * 32 + mi * 16 + quad * 4 + r] =
                    psum[mi][r];
    }
}

// ---------------------------------------------------------------------------
// Fold 1/Dcol into V (in place): Vt[b,h,k,s] *= 1/Dcol[b,h,s]
// ---------------------------------------------------------------------------
__global__ __launch_bounds__(256) void vscale(unsigned short* __restrict__ Vt,
                                              const float* __restrict__ Dcol) {
    const int k = blockIdx.x, bh = blockIdx.y, t = threadIdx.x;
    size_t base = ((size_t)bh * 64 + k) * 2048 + t * 8;
    bf16x8 v = *(const bf16x8*)&Vt[base];
    float4 d0 = *(const float4*)&Dcol[bh * 2048 + t * 8];
    float4 d1 = *(const float4*)&Dcol[bh * 2048 + t * 8 + 4];
    bf16x8 o;
    o[0] = (__bf16)((float)v[0] / d0.x);
    o[1] = (__bf16)((float)v[1] / d0.y);
    o[2] = (__bf16)((float)v[2] / d0.z);
    o[3] = (__bf16)((float)v[3] / d0.w);
    o[4] = (__bf16)((float)v[4] / d1.x);
    o[5] = (__bf16)((float)v[5] / d1.y);
    o[6] = (__bf16)((float)v[6] / d1.z);
    o[7] = (__bf16)((float)v[7] / d1.w);
    *(bf16x8*)&Vt[base] = o;
}

// ---------------------------------------------------------------------------
// attn*V via transposed tiles:
//   phase1: S^T[s,q] = K.Q^T  (A=K frags global->reg, B=Q frags reg-resident)
//           exp2 -> pack 4 consecutive s -> ds_write_b64 into Ps[q][s]
//   phase2: ctx^T[k,q] = V^T.P^T (A=V^T frags global->reg, B=Ps rows b128)
// LDS = Ps only. 2 barriers per s-tile. K prefetched one tile ahead.
// ---------------------------------------------------------------------------
__global__ __launch_bounds__(256) void attnpv(const unsigned short* __restrict__ Qh,
                                              const unsigned short* __restrict__ Kh,
                                              const unsigned short* __restrict__ Vn,
                                              unsigned short* __restrict__ Ctx) {
    const int tid = threadIdx.x;
    const int qt = blockIdx.x, bh = blockIdx.y;
    const int b = bh >> 4, h = bh & 15;
    const unsigned short* Qb = Qh + (size_t)bh * 2048 * 64;
    const unsigned short* Kb = Kh + (size_t)bh * 2048 * 64;
    const unsigned short* Vb = Vn + (size_t)bh * 64 * 2048;

    __shared__ __align__(16) unsigned short Ps[128 * 72];  // [q][s-tile 64], stride 144B

    const int lane = tid & 63, wid = tid >> 6;
    const int l16 = lane & 15, quad = lane >> 4;
    const int wq = wid & 1, ws = wid >> 1;   // q-half / (s-half, k-half)

    // Q B-frags for this wave's 64 q columns, register resident
    bf16x8 qf[2][4];
#pragma unroll
    for (int ks = 0; ks < 2; ++ks)
#pragma unroll
        for (int nj = 0; nj < 4; ++nj)
            qf[ks][nj] = ldfrag(&Qb[(size_t)(qt * 128 + wq * 64 + nj * 16 + l16) * 64 +
                                    ks * 32 + quad * 8]);

    const unsigned short* kp = Kb + (size_t)(ws * 32 + l16) * 64 + quad * 8;
    const unsigned short* vp = Vb + (size_t)(ws * 32 + l16) * 2048 + quad * 8;
    unsigned short* psw = &Ps[(size_t)(wq * 64 + l16) * 72 + ws * 32 + quad * 4];
    const unsigned short* psr = &Ps[(size_t)(wq * 64 + l16) * 72 + quad * 8];

    // preload K frags for s0 = 0
    bf16x8 kf[2][2];
#pragma unroll
    for (int mi = 0; mi < 2; ++mi)
#pragma unroll
        for (int ks = 0; ks < 2; ++ks)
            kf[mi][ks] = ldfrag(kp + mi * 1024 + ks * 32);

    f32x4 cacc[2][4] = {};
    for (int s0 = 0; s0 < 2048; s0 += 64) {
        // phase 1: S^T tile (64 s x 128 q), this wave: 32 s x 64 q
        f32x4 sacc[2][4] = {};
#pragma unroll
        for (int ks = 0; ks < 2; ++ks)
#pragma unroll
            for (int mi = 0; mi < 2; ++mi)
#pragma unroll
                for (int nj = 0; nj < 4; ++nj)
                    sacc[mi][nj] = MFMA(kf[mi][ks], qf[ks][nj], sacc[mi][nj]);

        // prefetch V^T frags for phase 2 (latency hidden under exp/pack)
        bf16x8 vf[2][2];
#pragma unroll
        for (int mi = 0; mi < 2; ++mi)
#pragma unroll
            for (int ks = 0; ks < 2; ++ks)
                vf[mi][ks] = ldfrag(vp + (size_t)mi * 32768 + ks * 32 + s0);
        // prefetch K frags for next s-tile
        const int s1 = (s0 + 64) & 2047;
#pragma unroll
        for (int mi = 0; mi < 2; ++mi)
#pragma unroll
            for (int ks = 0; ks < 2; ++ks)
                kf[mi][ks] = ldfrag(kp + (size_t)s1 * 64 + mi * 1024 + ks * 32);

        // exp2 + packed Ps write (4 consecutive s per lane -> b64)
#pragma unroll
        for (int mi = 0; mi < 2; ++mi)
#pragma unroll
            for (int nj = 0; nj < 4; ++nj) {
                ushort4 p;
                p.x = f2bf(fast_exp2(sacc[mi][nj][0]));
                p.y = f2bf(fast_exp2(sacc[mi][nj][1]));
                p.z = f2bf(fast_exp2(sacc[mi][nj][2]));
                p.w = f2bf(fast_exp2(sacc[mi][nj][3]));
                *(ushort4*)(psw + (size_t)nj * 16 * 72 + mi * 16) = p;
            }
        __syncthreads();

        // phase 2: ctx^T += V^T . P^T, this wave: 32 k x 64 q
        bf16x8 pf[2][4];
#pragma unroll
        for (int ks2 = 0; ks2 < 2; ++ks2)
#pragma unroll
            for (int nj = 0; nj < 4; ++nj)
                pf[ks2][nj] = ldfrag(psr + (size_t)nj * 16 * 72 + ks2 * 32);
#pragma unroll
        for (int ks2 = 0; ks2 < 2; ++ks2)
#pragma unroll
            for (int mi = 0; mi < 2; ++mi)
#pragma unroll
                for (int nj = 0; nj < 4; ++nj)
                    cacc[mi][nj] = MFMA(vf[mi][ks2], pf[ks2][nj], cacc[mi][nj]);
        __syncthreads();
    }

    // epilogue: cacc row = k (quad*4+r), col = q (l16); 4 consecutive k -> b64
#pragma unroll
    for (int mi = 0; mi < 2; ++mi)
#pragma unroll
        for (int nj = 0; nj < 4; ++nj) {
            int q = qt * 128 + wq * 64 + nj * 16 + l16;
            int k = ws * 32 + mi * 16 + quad * 4;
            ushort4 o;
            o.x = f2bf(cacc[mi][nj][0]);
            o.y = f2bf(cacc[mi][nj][1]);
            o.z = f2bf(cacc[mi][nj][2]);
            o.w = f2bf(cacc[mi][nj][3]);
            *(ushort4*)&Ctx[(size_t)(b * 2048 + q) * 1024 + h * 64 + k] = o;
        }
}

// ---------------------------------------------------------------------------
// Output GEMM: Out[8192 x 1024] f32 = Ctx(bf16) * Wo^T + bo
// ---------------------------------------------------------------------------
__global__ __launch_bounds__(256) void out_gemm(const unsigned short* __restrict__ A,
                                                const unsigned short* __restrict__ Bt,
                                                const float* __restrict__ bias,
                                                float* __restrict__ Out) {
    const int tid = threadIdx.x;
    const int bm = blockIdx.x, bn = blockIdx.y;

    __shared__ __align__(16) unsigned short As[128 * 40];
    __shared__ __align__(16) unsigned short Bs[128 * 40];

    const int lane = tid & 63, wid = tid >> 6;
    const int l16 = lane & 15, quad = lane >> 4;
    const int wm = wid & 1, wn = wid >> 1;

    f32x4 acc[4][4] = {};
    for (int kt = 0; kt < 32; ++kt) {
        __syncthreads();
        const int k0 = kt * 32;
#pragma unroll
        for (int i = 0; i < 2; ++i) {
            int seg = tid + i * 256;
            int row = seg >> 2, s4 = seg & 3;
            *(uint4*)&As[row * 40 + s4 * 8] =
                *(const uint4*)&A[(size_t)(bm * 128 + row) * 1024 + k0 + s4 * 8];
            *(uint4*)&Bs[row * 40 + s4 * 8] =
                *(const uint4*)&Bt[(size_t)(bn * 128 + row) * 1024 + k0 + s4 * 8];
        }
        __syncthreads();
        bf16x8 af[4], bfr[4];
#pragma unroll
        for (int mi = 0; mi < 4; ++mi)
            af[mi] = ldfrag(&As[(wm * 64 + mi * 16 + l16) * 40 + quad * 8]);
#pragma unroll
        for (int ni = 0; ni < 4; ++ni)
            bfr[ni] = ldfrag(&Bs[(wn * 64 + ni * 16 + l16) * 40 + quad * 8]);
#pragma unroll
        for (int mi = 0; mi < 4; ++mi)
#pragma unroll
            for (int ni = 0; ni < 4; ++ni)
                acc[mi][ni] = MFMA(af[mi], bfr[ni], acc[mi][ni]);
    }
#pragma unroll
    for (int mi = 0; mi < 4; ++mi)
#pragma unroll
        for (int ni = 0; ni < 4; ++ni)
#pragma unroll
            for (int r = 0; r < 4; ++r) {
                int row = bm * 128 + wm * 64 + mi * 16 + quad * 4 + r;
                int col = bn * 128 + wn * 64 + ni * 16 + l16;
                Out[(size_t)row * 1024 + col] = acc[mi][ni][r] + bias[col];
            }
}

// ---------------------------------------------------------------------------
extern "C" void kernel_launch(void* const* d_in, const int* in_sizes, int n_in,
                              void* d_out, int out_size, void* d_ws, size_t ws_size,
                              hipStream_t stream) {
    (void)in_sizes; (void)n_in; (void)out_size; (void)ws_size;
    const float* query = (const float*)d_in[0];
    const float* key_  = (const float*)d_in[1];
    const float* value = (const float*)d_in[2];
    const float* Wq    = (const float*)d_in[3];
    const float* bq    = (const float*)d_in[4];
    const float* Wk    = (const float*)d_in[5];
    const float* bk    = (const float*)d_in[6];
    const float* Wv    = (const float*)d_in[7];
    const float* bv    = (const float*)d_in[8];
    const float* Wo    = (const float*)d_in[9];
    const float* bo    = (const float*)d_in[10];
    float* Out = (float*)d_out;

    char* ws = (char*)d_ws;
    const size_t MB = 1024 * 1024;
    unsigned short* Wt   = (unsigned short*)(ws);             // 6 MB  [3][1024][1024] bf16
    unsigned short* Wot  = (unsigned short*)(ws + 6 * MB);    // 2 MB
    unsigned short* Qh   = (unsigned short*)(ws + 8 * MB);    // 16 MB [b,h,s,64] (pre-scaled)
    unsigned short* Kh   = (unsigned short*)(ws + 24 * MB);   // 16 MB
    unsigned short* Vt   = (unsigned short*)(ws + 40 * MB);   // 16 MB [b,h,64,s] -> Vn in place
    unsigned short* Ctx  = (unsigned short*)(ws + 56 * MB);   // 16 MB [b*s,1024]
    float* Dcol          = (float*)(ws + 72 * MB);            // 0.5 MB [b,h,s]

    wprep<<<dim3(4096, 4), dim3(256), 0, stream>>>(Wq, Wk, Wv, Wo, Wt, Wot);
    proj_gemm<<<dim3(64, 8, 3), dim3(256), 0, stream>>>(query, key_, value, Wt,
                                                        bq, bk, bv, Qh, Kh, Vt);
    colsum<<<dim3(16, 64), dim3(256), 0, stream>>>(Qh, Kh, Dcol);
    vscale<<<dim3(64, 64), dim3(256), 0, stream>>>(Vt, Dcol);
    attnpv<<<dim3(16, 64), dim3(256), 0, stream>>>(Qh, Kh, Vt, Ctx);
    out_gemm<<<dim3(64, 8), dim3(256), 0, stream>>>(Ctx, Wot, bo, Out);
}

// Round 4
// 482.413 us; speedup vs baseline: 1.1311x; 1.1311x over previous
//
#include <hip/hip_runtime.h>

// MultiHeadedAttention: B=4, S=2048, H=16, D_MODEL=1024, D_K=64
// Softmax over the QUERY axis (per key-column normalization).
// Pipeline: wprep -> 3x(xprep, proj_gemm) -> colsum_vscale -> attnpv -> out_gemm
// R4: - colsum reverted to LDS-cooperative Q staging (R2 zero-LDS form regressed
//       ~+50us: 4x redundant global streams, latency-bound), now with
//       global_load_lds width-16 staging + V-scale fused into epilogue
//     - proj/out_gemm: m97-style direct-to-LDS staging (unpadded 128x32 tiles,
//       global_load_lds 16B) -- measured 1.69x on this structure in learn_hip
//     - xprep converts X f32->bf16 per z into a buffer aliasing Ctx (ws<=72MB)
//     - attnpv unchanged (next round's target)

#define DEV __device__ __forceinline__

typedef __bf16 bf16x8 __attribute__((ext_vector_type(8)));
typedef float  f32x4  __attribute__((ext_vector_type(4)));

DEV unsigned short f2bf(float f) {
    __bf16 h = (__bf16)f;
    return __builtin_bit_cast(unsigned short, h);
}

DEV bf16x8 ldfrag(const unsigned short* p) {
    return *reinterpret_cast<const bf16x8*>(p);
}

DEV float fast_exp2(float x) {
#if __has_builtin(__builtin_amdgcn_exp2f)
    return __builtin_amdgcn_exp2f(x);
#else
    return exp2f(x);
#endif
}

// async global->LDS, 16B per lane; LDS dst = wave-uniform base + lane*16
DEV void gld16(const unsigned short* g, unsigned short* l) {
    __builtin_amdgcn_global_load_lds(
        (__attribute__((address_space(1))) void*)g,
        (__attribute__((address_space(3))) void*)l, 16, 0, 0);
}

#define MFMA(a,b,c) __builtin_amdgcn_mfma_f32_16x16x32_bf16((a),(b),(c),0,0,0)

// score*1/sqrt(64) then exp -> exp2(score * log2(e)/8); folded into Qh.
#define QSCALE 0.18033688011112042f

// ---------------------------------------------------------------------------
// Weight prep: Wq/Wk/Wv [16,1024,64] f32 -> Wt[z][n=h*64+k][m] bf16 (B^T layout)
//              Wo [1024,1024] f32 -> bf16 (already [n][m])
// ---------------------------------------------------------------------------
__global__ __launch_bounds__(256) void wprep(const float* __restrict__ Wq,
                                             const float* __restrict__ Wk,
                                             const float* __restrict__ Wv,
                                             const float* __restrict__ Wo,
                                             unsigned short* __restrict__ Wt,
                                             unsigned short* __restrict__ Wot) {
    int idx = blockIdx.x * 256 + threadIdx.x;   // < 1024*1024
    int which = blockIdx.y;
    if (which == 3) { Wot[idx] = f2bf(Wo[idx]); return; }
    const float* W = (which == 0) ? Wq : (which == 1) ? Wk : Wv;
    int n = idx >> 10, m = idx & 1023;
    int h = n >> 6, k = n & 63;
    Wt[(size_t)which * 1048576 + idx] = f2bf(W[h * 65536 + m * 64 + k]);
}

// ---------------------------------------------------------------------------
// X f32 -> bf16 (one input of 8192x1024 per launch)
// ---------------------------------------------------------------------------
__global__ __launch_bounds__(256) void xprep(const float* __restrict__ X,
                                             unsigned short* __restrict__ Xb) {
    int idx = (blockIdx.x * 256 + threadIdx.x) * 4;
    float4 f = *(const float4*)&X[idx];
    ushort4 o;
    o.x = f2bf(f.x); o.y = f2bf(f.y); o.z = f2bf(f.z); o.w = f2bf(f.w);
    *(ushort4*)&Xb[idx] = o;
}

// ---------------------------------------------------------------------------
// Projection GEMM (m97-style): C[8192x1024] = Xb * Bt^T + bias
// z=0 -> O=Qh[b,h,s,k] (pre-scaled by QSCALE); z=1 -> O=Kh; z=2 -> Vt[b,h,k,s]
// Unpadded 128x32 LDS tiles, global_load_lds width-16 staging.
// ---------------------------------------------------------------------------
__global__ __launch_bounds__(256) void proj_gemm(
        const unsigned short* __restrict__ Xb, const unsigned short* __restrict__ Bt,
        const float* __restrict__ bias, unsigned short* __restrict__ O,
        unsigned short* __restrict__ Vt, int z) {
    const int tid = threadIdx.x;
    const int bm = blockIdx.x, bn = blockIdx.y;

    __shared__ __align__(16) unsigned short As[128 * 32];
    __shared__ __align__(16) unsigned short Bs[128 * 32];

    const int lane = tid & 63, wid = tid >> 6;
    const int l16 = lane & 15, quad = lane >> 4;
    const int wm = wid & 1, wn = wid >> 1;

    const unsigned short* ga =
        Xb + (size_t)(bm * 128 + wid * 32 + (lane >> 2)) * 1024 + (lane & 3) * 8;
    const unsigned short* gb =
        Bt + (size_t)(bn * 128 + wid * 32 + (lane >> 2)) * 1024 + (lane & 3) * 8;
    unsigned short* la = &As[wid * 32 * 32];
    unsigned short* lb = &Bs[wid * 32 * 32];

    f32x4 acc[4][4] = {};
    for (int kt = 0; kt < 32; ++kt) {
        __syncthreads();
        const int k0 = kt * 32;
        gld16(ga + k0, la);
        gld16(ga + k0 + 16 * 1024, la + 16 * 32);
        gld16(gb + k0, lb);
        gld16(gb + k0 + 16 * 1024, lb + 16 * 32);
        __syncthreads();
        bf16x8 af[4], bfr[4];
#pragma unroll
        for (int mi = 0; mi < 4; ++mi)
            af[mi] = ldfrag(&As[(wm * 64 + mi * 16 + l16) * 32 + quad * 8]);
#pragma unroll
        for (int ni = 0; ni < 4; ++ni)
            bfr[ni] = ldfrag(&Bs[(wn * 64 + ni * 16 + l16) * 32 + quad * 8]);
#pragma unroll
        for (int mi = 0; mi < 4; ++mi)
#pragma unroll
            for (int ni = 0; ni < 4; ++ni)
                acc[mi][ni] = MFMA(af[mi], bfr[ni], acc[mi][ni]);
    }

#pragma unroll
    for (int mi = 0; mi < 4; ++mi)
#pragma unroll
        for (int ni = 0; ni < 4; ++ni)
#pragma unroll
            for (int r = 0; r < 4; ++r) {
                int row = bm * 128 + wm * 64 + mi * 16 + quad * 4 + r;  // flat b*s
                int col = bn * 128 + wn * 64 + ni * 16 + l16;           // h*64+k
                float v = acc[mi][ni][r] + bias[col];
                if (z == 0) v *= QSCALE;
                int b = row >> 11, s = row & 2047;
                int h = col >> 6, k = col & 63;
                unsigned short o = f2bf(v);
                if (z == 2) {
                    Vt[(size_t)((b * 16 + h) * 64 + k) * 2048 + s] = o;
                } else {
                    O[(size_t)((b * 16 + h) * 2048 + s) * 64 + k] = o;
                }
            }
}

// ---------------------------------------------------------------------------
// Column softmax denominators + V scaling fused:
//   Dcol[s] = sum_q exp2(S[q,s]); then Vt[bh,k,s-range] *= 1/Dcol[s] in place.
// K frags register-resident (B-operand); Q tiles LDS-cooperative via
// global_load_lds (two unpadded 128x32 halves -> m97 frag-read pattern).
// ---------------------------------------------------------------------------
__global__ __launch_bounds__(256) void colsum_vscale(
        const unsigned short* __restrict__ Qh, const unsigned short* __restrict__ Kh,
        unsigned short* __restrict__ Vt) {
    const int tid = threadIdx.x;
    const int st = blockIdx.x, bh = blockIdx.y;
    const unsigned short* Qb = Qh + (size_t)bh * 2048 * 64;
    const unsigned short* Kb = Kh + (size_t)bh * 2048 * 64;

    __shared__ __align__(16) unsigned short Qs[2 * 128 * 32];  // [ks][row][32]
    __shared__ float Dtmp[2][128];
    __shared__ float Dsh[128];

    const int lane = tid & 63, wid = tid >> 6;
    const int l16 = lane & 15, quad = lane >> 4;
    const int wm = wid & 1, wn = wid >> 1;

    // K B-frags for this wave's 64 s-columns, register resident
    bf16x8 kf[2][4];
#pragma unroll
    for (int ks = 0; ks < 2; ++ks)
#pragma unroll
        for (int ni = 0; ni < 4; ++ni)
            kf[ks][ni] = ldfrag(&Kb[(size_t)(st * 128 + wn * 64 + ni * 16 + l16) * 64 +
                                    ks * 32 + quad * 8]);

    const unsigned short* gq =
        Qb + (size_t)(wid * 32 + (lane >> 2)) * 64 + (lane & 3) * 8;

    float psum[4] = {0.f, 0.f, 0.f, 0.f};
    for (int q0 = 0; q0 < 2048; q0 += 128) {
        __syncthreads();
        // stage Q tile 128x64 as two 128x32 halves (global_load_lds, 4/wave)
#pragma unroll
        for (int ks = 0; ks < 2; ++ks) {
            gld16(gq + (size_t)q0 * 64 + ks * 32, &Qs[ks * 4096 + wid * 32 * 32]);
            gld16(gq + (size_t)(q0 + 16) * 64 + ks * 32,
                  &Qs[ks * 4096 + (wid * 32 + 16) * 32]);
        }
        __syncthreads();
        f32x4 acc[4][4] = {};
#pragma unroll
        for (int ks = 0; ks < 2; ++ks) {
            bf16x8 af[4];
#pragma unroll
            for (int mi = 0; mi < 4; ++mi)
                af[mi] = ldfrag(&Qs[ks * 4096 + (wm * 64 + mi * 16 + l16) * 32 + quad * 8]);
#pragma unroll
            for (int mi = 0; mi < 4; ++mi)
#pragma unroll
                for (int ni = 0; ni < 4; ++ni)
                    acc[mi][ni] = MFMA(af[mi], kf[ks][ni], acc[mi][ni]);
        }
#pragma unroll
        for (int ni = 0; ni < 4; ++ni) {
            float d = 0.f;
#pragma unroll
            for (int mi = 0; mi < 4; ++mi)
#pragma unroll
                for (int r = 0; r < 4; ++r)
                    d += fast_exp2(acc[mi][ni][r]);
            psum[ni] += d;
        }
    }
#pragma unroll
    for (int ni = 0; ni < 4; ++ni) {           // reduce over quad groups (rows)
        float v = psum[ni];
        v += __shfl_xor(v, 16, 64);
        v += __shfl_xor(v, 32, 64);
        if (quad == 0) Dtmp[wm][wn * 64 + ni * 16 + l16] = v;
    }
    __syncthreads();
    if (tid < 128) Dsh[tid] = 1.0f / (Dtmp[0][tid] + Dtmp[1][tid]);
    __syncthreads();

    // scale V in place: rows k=tid>>2 (64), s-chunk c=tid&3 (32 each)
    const int k = tid >> 2, c = tid & 3;
    unsigned short* vrow = Vt + ((size_t)bh * 64 + k) * 2048 + st * 128 + c * 32;
#pragma unroll
    for (int j = 0; j < 4; ++j) {
        bf16x8 v = *(const bf16x8*)&vrow[j * 8];
        bf16x8 o;
#pragma unroll
        for (int e = 0; e < 8; ++e)
            o[e] = (__bf16)((float)v[e] * Dsh[c * 32 + j * 8 + e]);
        *(bf16x8*)&vrow[j * 8] = o;
    }
}

// ---------------------------------------------------------------------------
// attn*V via transposed tiles (unchanged from R3):
//   phase1: S^T[s,q] = K.Q^T ; exp2 -> packed ds_write_b64 into Ps[q][s]
//   phase2: ctx^T[k,q] = V^T.P^T
// ---------------------------------------------------------------------------
__global__ __launch_bounds__(256) void attnpv(const unsigned short* __restrict__ Qh,
                                              const unsigned short* __restrict__ Kh,
                                              const unsigned short* __restrict__ Vn,
                                              unsigned short* __restrict__ Ctx) {
    const int tid = threadIdx.x;
    const int qt = blockIdx.x, bh = blockIdx.y;
    const int b = bh >> 4, h = bh & 15;
    const unsigned short* Qb = Qh + (size_t)bh * 2048 * 64;
    const unsigned short* Kb = Kh + (size_t)bh * 2048 * 64;
    const unsigned short* Vb = Vn + (size_t)bh * 64 * 2048;

    __shared__ __align__(16) unsigned short Ps[128 * 72];  // [q][s-tile 64]

    const int lane = tid & 63, wid = tid >> 6;
    const int l16 = lane & 15, quad = lane >> 4;
    const int wq = wid & 1, ws = wid >> 1;

    bf16x8 qf[2][4];
#pragma unroll
    for (int ks = 0; ks < 2; ++ks)
#pragma unroll
        for (int nj = 0; nj < 4; ++nj)
            qf[ks][nj] = ldfrag(&Qb[(size_t)(qt * 128 + wq * 64 + nj * 16 + l16) * 64 +
                                    ks * 32 + quad * 8]);

    const unsigned short* kp = Kb + (size_t)(ws * 32 + l16) * 64 + quad * 8;
    const unsigned short* vp = Vb + (size_t)(ws * 32 + l16) * 2048 + quad * 8;
    unsigned short* psw = &Ps[(size_t)(wq * 64 + l16) * 72 + ws * 32 + quad * 4];
    const unsigned short* psr = &Ps[(size_t)(wq * 64 + l16) * 72 + quad * 8];

    bf16x8 kf[2][2];
#pragma unroll
    for (int mi = 0; mi < 2; ++mi)
#pragma unroll
        for (int ks = 0; ks < 2; ++ks)
            kf[mi][ks] = ldfrag(kp + mi * 1024 + ks * 32);

    f32x4 cacc[2][4] = {};
    for (int s0 = 0; s0 < 2048; s0 += 64) {
        f32x4 sacc[2][4] = {};
#pragma unroll
        for (int ks = 0; ks < 2; ++ks)
#pragma unroll
            for (int mi = 0; mi < 2; ++mi)
#pragma unroll
                for (int nj = 0; nj < 4; ++nj)
                    sacc[mi][nj] = MFMA(kf[mi][ks], qf[ks][nj], sacc[mi][nj]);

        bf16x8 vf[2][2];
#pragma unroll
        for (int mi = 0; mi < 2; ++mi)
#pragma unroll
            for (int ks = 0; ks < 2; ++ks)
                vf[mi][ks] = ldfrag(vp + (size_t)mi * 32768 + ks * 32 + s0);
        const int s1 = (s0 + 64) & 2047;
#pragma unroll
        for (int mi = 0; mi < 2; ++mi)
#pragma unroll
            for (int ks = 0; ks < 2; ++ks)
                kf[mi][ks] = ldfrag(kp + (size_t)s1 * 64 + mi * 1024 + ks * 32);

#pragma unroll
        for (int mi = 0; mi < 2; ++mi)
#pragma unroll
            for (int nj = 0; nj < 4; ++nj) {
                ushort4 p;
                p.x = f2bf(fast_exp2(sacc[mi][nj][0]));
                p.y = f2bf(fast_exp2(sacc[mi][nj][1]));
                p.z = f2bf(fast_exp2(sacc[mi][nj][2]));
                p.w = f2bf(fast_exp2(sacc[mi][nj][3]));
                *(ushort4*)(psw + (size_t)nj * 16 * 72 + mi * 16) = p;
            }
        __syncthreads();

        bf16x8 pf[2][4];
#pragma unroll
        for (int ks2 = 0; ks2 < 2; ++ks2)
#pragma unroll
            for (int nj = 0; nj < 4; ++nj)
                pf[ks2][nj] = ldfrag(psr + (size_t)nj * 16 * 72 + ks2 * 32);
#pragma unroll
        for (int ks2 = 0; ks2 < 2; ++ks2)
#pragma unroll
            for (int mi = 0; mi < 2; ++mi)
#pragma unroll
                for (int nj = 0; nj < 4; ++nj)
                    cacc[mi][nj] = MFMA(vf[mi][ks2], pf[ks2][nj], cacc[mi][nj]);
        __syncthreads();
    }

#pragma unroll
    for (int mi = 0; mi < 2; ++mi)
#pragma unroll
        for (int nj = 0; nj < 4; ++nj) {
            int q = qt * 128 + wq * 64 + nj * 16 + l16;
            int k = ws * 32 + mi * 16 + quad * 4;
            ushort4 o;
            o.x = f2bf(cacc[mi][nj][0]);
            o.y = f2bf(cacc[mi][nj][1]);
            o.z = f2bf(cacc[mi][nj][2]);
            o.w = f2bf(cacc[mi][nj][3]);
            *(ushort4*)&Ctx[(size_t)(b * 2048 + q) * 1024 + h * 64 + k] = o;
        }
}

// ---------------------------------------------------------------------------
// Output GEMM (m97-style): Out[8192x1024] f32 = Ctx(bf16) * Wo^T + bo
// ---------------------------------------------------------------------------
__global__ __launch_bounds__(256) void out_gemm(const unsigned short* __restrict__ A,
                                                const unsigned short* __restrict__ Bt,
                                                const float* __restrict__ bias,
                                                float* __restrict__ Out) {
    const int tid = threadIdx.x;
    const int bm = blockIdx.x, bn = blockIdx.y;

    __shared__ __align__(16) unsigned short As[128 * 32];
    __shared__ __align__(16) unsigned short Bs[128 * 32];

    const int lane = tid & 63, wid = tid >> 6;
    const int l16 = lane & 15, quad = lane >> 4;
    const int wm = wid & 1, wn = wid >> 1;

    const unsigned short* ga =
        A + (size_t)(bm * 128 + wid * 32 + (lane >> 2)) * 1024 + (lane & 3) * 8;
    const unsigned short* gb =
        Bt + (size_t)(bn * 128 + wid * 32 + (lane >> 2)) * 1024 + (lane & 3) * 8;
    unsigned short* la = &As[wid * 32 * 32];
    unsigned short* lb = &Bs[wid * 32 * 32];

    f32x4 acc[4][4] = {};
    for (int kt = 0; kt < 32; ++kt) {
        __syncthreads();
        const int k0 = kt * 32;
        gld16(ga + k0, la);
        gld16(ga + k0 + 16 * 1024, la + 16 * 32);
        gld16(gb + k0, lb);
        gld16(gb + k0 + 16 * 1024, lb + 16 * 32);
        __syncthreads();
        bf16x8 af[4], bfr[4];
#pragma unroll
        for (int mi = 0; mi < 4; ++mi)
            af[mi] = ldfrag(&As[(wm * 64 + mi * 16 + l16) * 32 + quad * 8]);
#pragma unroll
        for (int ni = 0; ni < 4; ++ni)
            bfr[ni] = ldfrag(&Bs[(wn * 64 + ni * 16 + l16) * 32 + quad * 8]);
#pragma unroll
        for (int mi = 0; mi < 4; ++mi)
#pragma unroll
            for (int ni = 0; ni < 4; ++ni)
                acc[mi][ni] = MFMA(af[mi], bfr[ni], acc[mi][ni]);
    }
#pragma unroll
    for (int mi = 0; mi < 4; ++mi)
#pragma unroll
        for (int ni = 0; ni < 4; ++ni)
#pragma unroll
            for (int r = 0; r < 4; ++r) {
                int row = bm * 128 + wm * 64 + mi * 16 + quad * 4 + r;
                int col = bn * 128 + wn * 64 + ni * 16 + l16;
                Out[(size_t)row * 1024 + col] = acc[mi][ni][r] + bias[col];
            }
}

// ---------------------------------------------------------------------------
extern "C" void kernel_launch(void* const* d_in, const int* in_sizes, int n_in,
                              void* d_out, int out_size, void* d_ws, size_t ws_size,
                              hipStream_t stream) {
    (void)in_sizes; (void)n_in; (void)out_size; (void)ws_size;
    const float* X[3] = {(const float*)d_in[0], (const float*)d_in[1],
                         (const float*)d_in[2]};
    const float* Wq = (const float*)d_in[3];
    const float* bq = (const float*)d_in[4];
    const float* Wk = (const float*)d_in[5];
    const float* bk = (const float*)d_in[6];
    const float* Wv = (const float*)d_in[7];
    const float* bv = (const float*)d_in[8];
    const float* Wo = (const float*)d_in[9];
    const float* bo = (const float*)d_in[10];
    const float* bias[3] = {bq, bk, bv};
    float* Out = (float*)d_out;

    char* ws = (char*)d_ws;
    const size_t MB = 1024 * 1024;
    unsigned short* Wt  = (unsigned short*)(ws);            // 6 MB  [3][1024][1024] bf16
    unsigned short* Wot = (unsigned short*)(ws + 6 * MB);   // 2 MB
    unsigned short* Qh  = (unsigned short*)(ws + 8 * MB);   // 16 MB [b,h,s,64] (pre-scaled)
    unsigned short* Kh  = (unsigned short*)(ws + 24 * MB);  // 16 MB
    unsigned short* Vt  = (unsigned short*)(ws + 40 * MB);  // 16 MB [b,h,64,s] -> scaled in place
    unsigned short* Ctx = (unsigned short*)(ws + 56 * MB);  // 16 MB [b*s,1024]
    unsigned short* Xb  = Ctx;                              // alias: Xb dead before Ctx live
    unsigned short* Oz[3] = {Qh, Kh, Qh /*unused for z=2*/};

    wprep<<<dim3(4096, 4), dim3(256), 0, stream>>>(Wq, Wk, Wv, Wo, Wt, Wot);
    for (int z = 0; z < 3; ++z) {
        xprep<<<dim3(8192), dim3(256), 0, stream>>>(X[z], Xb);
        proj_gemm<<<dim3(64, 8), dim3(256), 0, stream>>>(
            Xb, Wt + (size_t)z * 1048576, bias[z], Oz[z], Vt, z);
    }
    colsum_vscale<<<dim3(16, 64), dim3(256), 0, stream>>>(Qh, Kh, Vt);
    attnpv<<<dim3(16, 64), dim3(256), 0, stream>>>(Qh, Kh, Vt, Ctx);
    out_gemm<<<dim3(64, 8), dim3(256), 0, stream>>>(Ctx, Wot, bo, Out);
}

// Round 5
// 456.566 us; speedup vs baseline: 1.1952x; 1.0566x over previous
//
#include <hip/hip_runtime.h>

// MultiHeadedAttention: B=4, S=2048, H=16, D_MODEL=1024, D_K=64
// Softmax over the QUERY axis (per key-column normalization).
// Pipeline: wprep -> 3x(xprep, proj_gemm) -> colsum_vscale -> attnpv -> out_gemm
// R5: - attnpv: K/V tiles staged in LDS via global_load_lds, double-buffered
//       (halves redundant L2/L3 streaming; prefetch overlaps phase-2),
//       Ps XOR-swizzle kills 4-way bank conflicts
//     - colsum_vscale: double-buffered Q staging -> 1 barrier/iter, loads
//       overlap the MFMA+exp body (R4 shape had zero overlap)

#define DEV __device__ __forceinline__

typedef __bf16 bf16x8 __attribute__((ext_vector_type(8)));
typedef float  f32x4  __attribute__((ext_vector_type(4)));

DEV unsigned short f2bf(float f) {
    __bf16 h = (__bf16)f;
    return __builtin_bit_cast(unsigned short, h);
}

DEV bf16x8 ldfrag(const unsigned short* p) {
    return *reinterpret_cast<const bf16x8*>(p);
}

DEV float fast_exp2(float x) {
#if __has_builtin(__builtin_amdgcn_exp2f)
    return __builtin_amdgcn_exp2f(x);
#else
    return exp2f(x);
#endif
}

// async global->LDS, 16B per lane; LDS dst = wave-uniform base + lane*16
DEV void gld16(const unsigned short* g, unsigned short* l) {
    __builtin_amdgcn_global_load_lds(
        (__attribute__((address_space(1))) void*)g,
        (__attribute__((address_space(3))) void*)l, 16, 0, 0);
}

#define MFMA(a,b,c) __builtin_amdgcn_mfma_f32_16x16x32_bf16((a),(b),(c),0,0,0)

// score*1/sqrt(64) then exp -> exp2(score * log2(e)/8); folded into Qh.
#define QSCALE 0.18033688011112042f

// ---------------------------------------------------------------------------
// Weight prep: Wq/Wk/Wv [16,1024,64] f32 -> Wt[z][n=h*64+k][m] bf16 (B^T layout)
//              Wo [1024,1024] f32 -> bf16 (already [n][m])
// ---------------------------------------------------------------------------
__global__ __launch_bounds__(256) void wprep(const float* __restrict__ Wq,
                                             const float* __restrict__ Wk,
                                             const float* __restrict__ Wv,
                                             const float* __restrict__ Wo,
                                             unsigned short* __restrict__ Wt,
                                             unsigned short* __restrict__ Wot) {
    int idx = blockIdx.x * 256 + threadIdx.x;   // < 1024*1024
    int which = blockIdx.y;
    if (which == 3) { Wot[idx] = f2bf(Wo[idx]); return; }
    const float* W = (which == 0) ? Wq : (which == 1) ? Wk : Wv;
    int n = idx >> 10, m = idx & 1023;
    int h = n >> 6, k = n & 63;
    Wt[(size_t)which * 1048576 + idx] = f2bf(W[h * 65536 + m * 64 + k]);
}

// ---------------------------------------------------------------------------
// X f32 -> bf16 (one input of 8192x1024 per launch)
// ---------------------------------------------------------------------------
__global__ __launch_bounds__(256) void xprep(const float* __restrict__ X,
                                             unsigned short* __restrict__ Xb) {
    int idx = (blockIdx.x * 256 + threadIdx.x) * 4;
    float4 f = *(const float4*)&X[idx];
    ushort4 o;
    o.x = f2bf(f.x); o.y = f2bf(f.y); o.z = f2bf(f.z); o.w = f2bf(f.w);
    *(ushort4*)&Xb[idx] = o;
}

// ---------------------------------------------------------------------------
// Projection GEMM (m97-style): C[8192x1024] = Xb * Bt^T + bias
// z=0 -> O=Qh[b,h,s,k] (pre-scaled by QSCALE); z=1 -> O=Kh; z=2 -> Vt[b,h,k,s]
// ---------------------------------------------------------------------------
__global__ __launch_bounds__(256) void proj_gemm(
        const unsigned short* __restrict__ Xb, const unsigned short* __restrict__ Bt,
        const float* __restrict__ bias, unsigned short* __restrict__ O,
        unsigned short* __restrict__ Vt, int z) {
    const int tid = threadIdx.x;
    const int bm = blockIdx.x, bn = blockIdx.y;

    __shared__ __align__(16) unsigned short As[128 * 32];
    __shared__ __align__(16) unsigned short Bs[128 * 32];

    const int lane = tid & 63, wid = tid >> 6;
    const int l16 = lane & 15, quad = lane >> 4;
    const int wm = wid & 1, wn = wid >> 1;

    const unsigned short* ga =
        Xb + (size_t)(bm * 128 + wid * 32 + (lane >> 2)) * 1024 + (lane & 3) * 8;
    const unsigned short* gb =
        Bt + (size_t)(bn * 128 + wid * 32 + (lane >> 2)) * 1024 + (lane & 3) * 8;
    unsigned short* la = &As[wid * 32 * 32];
    unsigned short* lb = &Bs[wid * 32 * 32];

    f32x4 acc[4][4] = {};
    for (int kt = 0; kt < 32; ++kt) {
        __syncthreads();
        const int k0 = kt * 32;
        gld16(ga + k0, la);
        gld16(ga + k0 + 16 * 1024, la + 16 * 32);
        gld16(gb + k0, lb);
        gld16(gb + k0 + 16 * 1024, lb + 16 * 32);
        __syncthreads();
        bf16x8 af[4], bfr[4];
#pragma unroll
        for (int mi = 0; mi < 4; ++mi)
            af[mi] = ldfrag(&As[(wm * 64 + mi * 16 + l16) * 32 + quad * 8]);
#pragma unroll
        for (int ni = 0; ni < 4; ++ni)
            bfr[ni] = ldfrag(&Bs[(wn * 64 + ni * 16 + l16) * 32 + quad * 8]);
#pragma unroll
        for (int mi = 0; mi < 4; ++mi)
#pragma unroll
            for (int ni = 0; ni < 4; ++ni)
                acc[mi][ni] = MFMA(af[mi], bfr[ni], acc[mi][ni]);
    }

#pragma unroll
    for (int mi = 0; mi < 4; ++mi)
#pragma unroll
        for (int ni = 0; ni < 4; ++ni)
#pragma unroll
            for (int r = 0; r < 4; ++r) {
                int row = bm * 128 + wm * 64 + mi * 16 + quad * 4 + r;  // flat b*s
                int col = bn * 128 + wn * 64 + ni * 16 + l16;           // h*64+k
                float v = acc[mi][ni][r] + bias[col];
                if (z == 0) v *= QSCALE;
                int b = row >> 11, s = row & 2047;
                int h = col >> 6, k = col & 63;
                unsigned short o = f2bf(v);
                if (z == 2) {
                    Vt[(size_t)((b * 16 + h) * 64 + k) * 2048 + s] = o;
                } else {
                    O[(size_t)((b * 16 + h) * 2048 + s) * 64 + k] = o;
                }
            }
}

// ---------------------------------------------------------------------------
// Column softmax denominators + V scaling fused, double-buffered Q staging:
//   Dcol[s] = sum_q exp2(S[q,s]); then Vt[bh,k,s-range] *= 1/Dcol[s].
// 1 barrier per q-tile; gld16 prefetch overlaps MFMA+exp body.
// ---------------------------------------------------------------------------
__global__ __launch_bounds__(256) void colsum_vscale(
        const unsigned short* __restrict__ Qh, const unsigned short* __restrict__ Kh,
        unsigned short* __restrict__ Vt) {
    const int tid = threadIdx.x;
    const int st = blockIdx.x, bh = blockIdx.y;
    const unsigned short* Qb = Qh + (size_t)bh * 2048 * 64;
    const unsigned short* Kb = Kh + (size_t)bh * 2048 * 64;

    __shared__ __align__(16) unsigned short Qs[2][2][128 * 32];  // [buf][ks][row*32]
    __shared__ float Dtmp[2][128];
    __shared__ float Dsh[128];

    const int lane = tid & 63, wid = tid >> 6;
    const int l16 = lane & 15, quad = lane >> 4;
    const int wm = wid & 1, wn = wid >> 1;

    // K B-frags for this wave's 64 s-columns, register resident
    bf16x8 kf[2][4];
#pragma unroll
    for (int ks = 0; ks < 2; ++ks)
#pragma unroll
        for (int ni = 0; ni < 4; ++ni)
            kf[ks][ni] = ldfrag(&Kb[(size_t)(st * 128 + wn * 64 + ni * 16 + l16) * 64 +
                                    ks * 32 + quad * 8]);

    const unsigned short* gq =
        Qb + (size_t)(wid * 32 + (lane >> 2)) * 64 + (lane & 3) * 8;

    // prologue: stage tile 0 into buf 0
#pragma unroll
    for (int ks = 0; ks < 2; ++ks) {
        gld16(gq + ks * 32, &Qs[0][ks][wid * 32 * 32]);
        gld16(gq + (size_t)16 * 64 + ks * 32, &Qs[0][ks][(wid * 32 + 16) * 32]);
    }

    float psum[4] = {0.f, 0.f, 0.f, 0.f};
    for (int it = 0; it < 16; ++it) {
        const int buf = it & 1;
        __syncthreads();   // tile `it` staged (vmcnt drain); buf^1 reads done
        if (it < 15) {
            const size_t q1 = (size_t)(it + 1) * 128;
#pragma unroll
            for (int ks = 0; ks < 2; ++ks) {
                gld16(gq + q1 * 64 + ks * 32, &Qs[buf ^ 1][ks][wid * 32 * 32]);
                gld16(gq + (q1 + 16) * 64 + ks * 32,
                      &Qs[buf ^ 1][ks][(wid * 32 + 16) * 32]);
            }
        }
        f32x4 acc[4][4] = {};
#pragma unroll
        for (int ks = 0; ks < 2; ++ks) {
            bf16x8 af[4];
#pragma unroll
            for (int mi = 0; mi < 4; ++mi)
                af[mi] = ldfrag(&Qs[buf][ks][(wm * 64 + mi * 16 + l16) * 32 + quad * 8]);
#pragma unroll
            for (int mi = 0; mi < 4; ++mi)
#pragma unroll
                for (int ni = 0; ni < 4; ++ni)
                    acc[mi][ni] = MFMA(af[mi], kf[ks][ni], acc[mi][ni]);
        }
#pragma unroll
        for (int ni = 0; ni < 4; ++ni) {
            float d = 0.f;
#pragma unroll
            for (int mi = 0; mi < 4; ++mi)
#pragma unroll
                for (int r = 0; r < 4; ++r)
                    d += fast_exp2(acc[mi][ni][r]);
            psum[ni] += d;
        }
    }
#pragma unroll
    for (int ni = 0; ni < 4; ++ni) {           // reduce over quad groups (rows)
        float v = psum[ni];
        v += __shfl_xor(v, 16, 64);
        v += __shfl_xor(v, 32, 64);
        if (quad == 0) Dtmp[wm][wn * 64 + ni * 16 + l16] = v;
    }
    __syncthreads();
    if (tid < 128) Dsh[tid] = 1.0f / (Dtmp[0][tid] + Dtmp[1][tid]);
    __syncthreads();

    // scale V in place: rows k=tid>>2 (64), s-chunk c=tid&3 (32 each)
    const int k = tid >> 2, c = tid & 3;
    unsigned short* vrow = Vt + ((size_t)bh * 64 + k) * 2048 + st * 128 + c * 32;
#pragma unroll
    for (int j = 0; j < 4; ++j) {
        bf16x8 v = *(const bf16x8*)&vrow[j * 8];
        bf16x8 o;
#pragma unroll
        for (int e = 0; e < 8; ++e)
            o[e] = (__bf16)((float)v[e] * Dsh[c * 32 + j * 8 + e]);
        *(bf16x8*)&vrow[j * 8] = o;
    }
}

// ---------------------------------------------------------------------------
// attn*V via transposed tiles, LDS-staged K/V (double-buffered):
//   phase1: S^T[s,q] = K.Q^T ; exp2 -> packed ds_write_b64 into Ps (swizzled)
//   phase2: ctx^T[k,q] = V^T.P^T
// Waves 0,1 stage K halves; waves 2,3 stage V halves (gld16). Prefetch for
// tile i+1 issued after bar B -> overlaps phase 2, drains at bar A(i+1).
// ---------------------------------------------------------------------------
__global__ __launch_bounds__(256) void attnpv(const unsigned short* __restrict__ Qh,
                                              const unsigned short* __restrict__ Kh,
                                              const unsigned short* __restrict__ Vn,
                                              unsigned short* __restrict__ Ctx) {
    const int tid = threadIdx.x;
    const int qt = blockIdx.x, bh = blockIdx.y;
    const int b = bh >> 4, h = bh & 15;
    const unsigned short* Qb = Qh + (size_t)bh * 2048 * 64;
    const unsigned short* Kb = Kh + (size_t)bh * 2048 * 64;
    const unsigned short* Vb = Vn + (size_t)bh * 64 * 2048;

    __shared__ __align__(16) unsigned short Ks[2][2][64 * 32];  // [buf][ks][s*32]
    __shared__ __align__(16) unsigned short Vs[2][2][64 * 32];  // [buf][ks2][k*32]
    __shared__ __align__(16) unsigned short Ps[128 * 72];       // [q][s^swz]

    const int lane = tid & 63, wid = tid >> 6;
    const int l16 = lane & 15, quad = lane >> 4;
    const int wq = wid & 1, ws = wid >> 1;
    const int swz = (l16 & 3) << 3;        // Ps column swizzle (16B-preserving)

    // Q B-frags for this wave's 64 q columns, register resident
    bf16x8 qf[2][4];
#pragma unroll
    for (int ks = 0; ks < 2; ++ks)
#pragma unroll
        for (int nj = 0; nj < 4; ++nj)
            qf[ks][nj] = ldfrag(&Qb[(size_t)(qt * 128 + wq * 64 + nj * 16 + l16) * 64 +
                                    ks * 32 + quad * 8]);

    // staging role: wid 0,1 -> K half wid; wid 2,3 -> V half wid-2
    const int srow = lane >> 2, scol = (lane & 3) * 8, half = wid & 1;
    const unsigned short* gk = Kb + (size_t)srow * 64 + half * 32 + scol;
    const unsigned short* gv = Vb + (size_t)srow * 2048 + half * 32 + scol;

    // prologue: stage tile 0 into buf 0
    if (wid < 2) {
#pragma unroll
        for (int gi = 0; gi < 4; ++gi)
            gld16(gk + (size_t)gi * 16 * 64, &Ks[0][half][gi * 16 * 32]);
    } else {
#pragma unroll
        for (int gi = 0; gi < 4; ++gi)
            gld16(gv + (size_t)gi * 16 * 2048, &Vs[0][half][gi * 16 * 32]);
    }

    f32x4 cacc[2][4] = {};
    for (int it = 0; it < 32; ++it) {
        const int buf = it & 1;
        const int s0 = it * 64;
        __syncthreads();   // bar A: tile `it` staged; Ps reads of it-1 done

        // phase 1: S^T tile (64 s x 128 q), this wave: 32 s x 64 q
        bf16x8 kf[2][2];
#pragma unroll
        for (int mi = 0; mi < 2; ++mi)
#pragma unroll
            for (int ks = 0; ks < 2; ++ks)
                kf[mi][ks] = ldfrag(&Ks[buf][ks][(ws * 32 + mi * 16 + l16) * 32 + quad * 8]);
        f32x4 sacc[2][4] = {};
#pragma unroll
        for (int ks = 0; ks < 2; ++ks)
#pragma unroll
            for (int mi = 0; mi < 2; ++mi)
#pragma unroll
                for (int nj = 0; nj < 4; ++nj)
                    sacc[mi][nj] = MFMA(kf[mi][ks], qf[ks][nj], sacc[mi][nj]);

        // exp2 + packed Ps write (4 consecutive s per lane -> b64, swizzled col)
#pragma unroll
        for (int mi = 0; mi < 2; ++mi)
#pragma unroll
            for (int nj = 0; nj < 4; ++nj) {
                ushort4 p;
                p.x = f2bf(fast_exp2(sacc[mi][nj][0]));
                p.y = f2bf(fast_exp2(sacc[mi][nj][1]));
                p.z = f2bf(fast_exp2(sacc[mi][nj][2]));
                p.w = f2bf(fast_exp2(sacc[mi][nj][3]));
                *(ushort4*)&Ps[(size_t)(wq * 64 + nj * 16 + l16) * 72 +
                               ((ws * 32 + mi * 16 + quad * 4) ^ swz)] = p;
            }
        __syncthreads();   // bar B: Ps ready; Ks[buf] reads done

        // prefetch tile it+1 into buf^1 (overlaps phase 2; drains at bar A)
        if (it < 31) {
            if (wid < 2) {
#pragma unroll
                for (int gi = 0; gi < 4; ++gi)
                    gld16(gk + (size_t)(s0 + 64 + gi * 16) * 64,
                          &Ks[buf ^ 1][half][gi * 16 * 32]);
            } else {
#pragma unroll
                for (int gi = 0; gi < 4; ++gi)
                    gld16(gv + (size_t)(gi * 16) * 2048 + s0 + 64,
                          &Vs[buf ^ 1][half][gi * 16 * 32]);
            }
        }

        // phase 2: ctx^T += V^T . P^T, this wave: 32 k x 64 q
        bf16x8 vf[2][2], pf[2][4];
#pragma unroll
        for (int mi = 0; mi < 2; ++mi)
#pragma unroll
            for (int ks2 = 0; ks2 < 2; ++ks2)
                vf[mi][ks2] = ldfrag(&Vs[buf][ks2][(ws * 32 + mi * 16 + l16) * 32 + quad * 8]);
#pragma unroll
        for (int ks2 = 0; ks2 < 2; ++ks2)
#pragma unroll
            for (int nj = 0; nj < 4; ++nj)
                pf[ks2][nj] = ldfrag(&Ps[(size_t)(wq * 64 + nj * 16 + l16) * 72 +
                                         ((ks2 * 32 + quad * 8) ^ swz)]);
#pragma unroll
        for (int ks2 = 0; ks2 < 2; ++ks2)
#pragma unroll
            for (int mi = 0; mi < 2; ++mi)
#pragma unroll
                for (int nj = 0; nj < 4; ++nj)
                    cacc[mi][nj] = MFMA(vf[mi][ks2], pf[ks2][nj], cacc[mi][nj]);
    }

    // epilogue: cacc row = k (quad*4+r), col = q (l16); 4 consecutive k -> b64
#pragma unroll
    for (int mi = 0; mi < 2; ++mi)
#pragma unroll
        for (int nj = 0; nj < 4; ++nj) {
            int q = qt * 128 + wq * 64 + nj * 16 + l16;
            int k = ws * 32 + mi * 16 + quad * 4;
            ushort4 o;
            o.x = f2bf(cacc[mi][nj][0]);
            o.y = f2bf(cacc[mi][nj][1]);
            o.z = f2bf(cacc[mi][nj][2]);
            o.w = f2bf(cacc[mi][nj][3]);
            *(ushort4*)&Ctx[(size_t)(b * 2048 + q) * 1024 + h * 64 + k] = o;
        }
}

// ---------------------------------------------------------------------------
// Output GEMM (m97-style): Out[8192x1024] f32 = Ctx(bf16) * Wo^T + bo
// ---------------------------------------------------------------------------
__global__ __launch_bounds__(256) void out_gemm(const unsigned short* __restrict__ A,
                                                const unsigned short* __restrict__ Bt,
                                                const float* __restrict__ bias,
                                                float* __restrict__ Out) {
    const int tid = threadIdx.x;
    const int bm = blockIdx.x, bn = blockIdx.y;

    __shared__ __align__(16) unsigned short As[128 * 32];
    __shared__ __align__(16) unsigned short Bs[128 * 32];

    const int lane = tid & 63, wid = tid >> 6;
    const int l16 = lane & 15, quad = lane >> 4;
    const int wm = wid & 1, wn = wid >> 1;

    const unsigned short* ga =
        A + (size_t)(bm * 128 + wid * 32 + (lane >> 2)) * 1024 + (lane & 3) * 8;
    const unsigned short* gb =
        Bt + (size_t)(bn * 128 + wid * 32 + (lane >> 2)) * 1024 + (lane & 3) * 8;
    unsigned short* la = &As[wid * 32 * 32];
    unsigned short* lb = &Bs[wid * 32 * 32];

    f32x4 acc[4][4] = {};
    for (int kt = 0; kt < 32; ++kt) {
        __syncthreads();
        const int k0 = kt * 32;
        gld16(ga + k0, la);
        gld16(ga + k0 + 16 * 1024, la + 16 * 32);
        gld16(gb + k0, lb);
        gld16(gb + k0 + 16 * 1024, lb + 16 * 32);
        __syncthreads();
        bf16x8 af[4], bfr[4];
#pragma unroll
        for (int mi = 0; mi < 4; ++mi)
            af[mi] = ldfrag(&As[(wm * 64 + mi * 16 + l16) * 32 + quad * 8]);
#pragma unroll
        for (int ni = 0; ni < 4; ++ni)
            bfr[ni] = ldfrag(&Bs[(wn * 64 + ni * 16 + l16) * 32 + quad * 8]);
#pragma unroll
        for (int mi = 0; mi < 4; ++mi)
#pragma unroll
            for (int ni = 0; ni < 4; ++ni)
                acc[mi][ni] = MFMA(af[mi], bfr[ni], acc[mi][ni]);
    }
#pragma unroll
    for (int mi = 0; mi < 4; ++mi)
#pragma unroll
        for (int ni = 0; ni < 4; ++ni)
#pragma unroll
            for (int r = 0; r < 4; ++r) {
                int row = bm * 128 + wm * 64 + mi * 16 + quad * 4 + r;
                int col = bn * 128 + wn * 64 + ni * 16 + l16;
                Out[(size_t)row * 1024 + col] = acc[mi][ni][r] + bias[col];
            }
}

// ---------------------------------------------------------------------------
extern "C" void kernel_launch(void* const* d_in, const int* in_sizes, int n_in,
                              void* d_out, int out_size, void* d_ws, size_t ws_size,
                              hipStream_t stream) {
    (void)in_sizes; (void)n_in; (void)out_size; (void)ws_size;
    const float* X[3] = {(const float*)d_in[0], (const float*)d_in[1],
                         (const float*)d_in[2]};
    const float* Wq = (const float*)d_in[3];
    const float* bq = (const float*)d_in[4];
    const float* Wk = (const float*)d_in[5];
    const float* bk = (const float*)d_in[6];
    const float* Wv = (const float*)d_in[7];
    const float* bv = (const float*)d_in[8];
    const float* Wo = (const float*)d_in[9];
    const float* bo = (const float*)d_in[10];
    const float* bias[3] = {bq, bk, bv};
    float* Out = (float*)d_out;

    char* ws = (char*)d_ws;
    const size_t MB = 1024 * 1024;
    unsigned short* Wt  = (unsigned short*)(ws);            // 6 MB  [3][1024][1024] bf16
    unsigned short* Wot = (unsigned short*)(ws + 6 * MB);   // 2 MB
    unsigned short* Qh  = (unsigned short*)(ws + 8 * MB);   // 16 MB [b,h,s,64] (pre-scaled)
    unsigned short* Kh  = (unsigned short*)(ws + 24 * MB);  // 16 MB
    unsigned short* Vt  = (unsigned short*)(ws + 40 * MB);  // 16 MB [b,h,64,s] -> scaled in place
    unsigned short* Ctx = (unsigned short*)(ws + 56 * MB);  // 16 MB [b*s,1024]
    unsigned short* Xb  = Ctx;                              // alias: Xb dead before Ctx live
    unsigned short* Oz[3] = {Qh, Kh, Qh /*unused for z=2*/};

    wprep<<<dim3(4096, 4), dim3(256), 0, stream>>>(Wq, Wk, Wv, Wo, Wt, Wot);
    for (int z = 0; z < 3; ++z) {
        xprep<<<dim3(8192), dim3(256), 0, stream>>>(X[z], Xb);
        proj_gemm<<<dim3(64, 8), dim3(256), 0, stream>>>(
            Xb, Wt + (size_t)z * 1048576, bias[z], Oz[z], Vt, z);
    }
    colsum_vscale<<<dim3(16, 64), dim3(256), 0, stream>>>(Qh, Kh, Vt);
    attnpv<<<dim3(16, 64), dim3(256), 0, stream>>>(Qh, Kh, Vt, Ctx);
    out_gemm<<<dim3(64, 8), dim3(256), 0, stream>>>(Ctx, Wot, bo, Out);
}

// Round 6
// 454.070 us; speedup vs baseline: 1.2017x; 1.0055x over previous
//
#include <hip/hip_runtime.h>

// MultiHeadedAttention: B=4, S=2048, H=16, D_MODEL=1024, D_K=64
// Softmax over the QUERY axis (per key-column normalization).
// Pipeline: wprep -> 3x(xprep, proj_gemm) -> colsum_vscale -> attnpv -> out_gemm
// R6: attnpv software-pipelined: phase1(i) [S^T=K.Q^T, exp->Ps] and
//     phase2(i-1) [ctx^T += V^T.P^T] share one barrier segment; Ps
//     double-buffered -> 1 barrier/iter (was 2), phase2 MFMA overlaps
//     phase1's exp VALU chain. K/V prefetch unchanged (full-iter cover).

#define DEV __device__ __forceinline__

typedef __bf16 bf16x8 __attribute__((ext_vector_type(8)));
typedef float  f32x4  __attribute__((ext_vector_type(4)));

DEV unsigned short f2bf(float f) {
    __bf16 h = (__bf16)f;
    return __builtin_bit_cast(unsigned short, h);
}

DEV bf16x8 ldfrag(const unsigned short* p) {
    return *reinterpret_cast<const bf16x8*>(p);
}

DEV float fast_exp2(float x) {
#if __has_builtin(__builtin_amdgcn_exp2f)
    return __builtin_amdgcn_exp2f(x);
#else
    return exp2f(x);
#endif
}

// async global->LDS, 16B per lane; LDS dst = wave-uniform base + lane*16
DEV void gld16(const unsigned short* g, unsigned short* l) {
    __builtin_amdgcn_global_load_lds(
        (__attribute__((address_space(1))) void*)g,
        (__attribute__((address_space(3))) void*)l, 16, 0, 0);
}

#define MFMA(a,b,c) __builtin_amdgcn_mfma_f32_16x16x32_bf16((a),(b),(c),0,0,0)

// score*1/sqrt(64) then exp -> exp2(score * log2(e)/8); folded into Qh.
#define QSCALE 0.18033688011112042f

// ---------------------------------------------------------------------------
// Weight prep: Wq/Wk/Wv [16,1024,64] f32 -> Wt[z][n=h*64+k][m] bf16 (B^T layout)
//              Wo [1024,1024] f32 -> bf16 (already [n][m])
// ---------------------------------------------------------------------------
__global__ __launch_bounds__(256) void wprep(const float* __restrict__ Wq,
                                             const float* __restrict__ Wk,
                                             const float* __restrict__ Wv,
                                             const float* __restrict__ Wo,
                                             unsigned short* __restrict__ Wt,
                                             unsigned short* __restrict__ Wot) {
    int idx = blockIdx.x * 256 + threadIdx.x;   // < 1024*1024
    int which = blockIdx.y;
    if (which == 3) { Wot[idx] = f2bf(Wo[idx]); return; }
    const float* W = (which == 0) ? Wq : (which == 1) ? Wk : Wv;
    int n = idx >> 10, m = idx & 1023;
    int h = n >> 6, k = n & 63;
    Wt[(size_t)which * 1048576 + idx] = f2bf(W[h * 65536 + m * 64 + k]);
}

// ---------------------------------------------------------------------------
// X f32 -> bf16 (one input of 8192x1024 per launch)
// ---------------------------------------------------------------------------
__global__ __launch_bounds__(256) void xprep(const float* __restrict__ X,
                                             unsigned short* __restrict__ Xb) {
    int idx = (blockIdx.x * 256 + threadIdx.x) * 4;
    float4 f = *(const float4*)&X[idx];
    ushort4 o;
    o.x = f2bf(f.x); o.y = f2bf(f.y); o.z = f2bf(f.z); o.w = f2bf(f.w);
    *(ushort4*)&Xb[idx] = o;
}

// ---------------------------------------------------------------------------
// Projection GEMM (m97-style): C[8192x1024] = Xb * Bt^T + bias
// z=0 -> O=Qh[b,h,s,k] (pre-scaled by QSCALE); z=1 -> O=Kh; z=2 -> Vt[b,h,k,s]
// ---------------------------------------------------------------------------
__global__ __launch_bounds__(256) void proj_gemm(
        const unsigned short* __restrict__ Xb, const unsigned short* __restrict__ Bt,
        const float* __restrict__ bias, unsigned short* __restrict__ O,
        unsigned short* __restrict__ Vt, int z) {
    const int tid = threadIdx.x;
    const int bm = blockIdx.x, bn = blockIdx.y;

    __shared__ __align__(16) unsigned short As[128 * 32];
    __shared__ __align__(16) unsigned short Bs[128 * 32];

    const int lane = tid & 63, wid = tid >> 6;
    const int l16 = lane & 15, quad = lane >> 4;
    const int wm = wid & 1, wn = wid >> 1;

    const unsigned short* ga =
        Xb + (size_t)(bm * 128 + wid * 32 + (lane >> 2)) * 1024 + (lane & 3) * 8;
    const unsigned short* gb =
        Bt + (size_t)(bn * 128 + wid * 32 + (lane >> 2)) * 1024 + (lane & 3) * 8;
    unsigned short* la = &As[wid * 32 * 32];
    unsigned short* lb = &Bs[wid * 32 * 32];

    f32x4 acc[4][4] = {};
    for (int kt = 0; kt < 32; ++kt) {
        __syncthreads();
        const int k0 = kt * 32;
        gld16(ga + k0, la);
        gld16(ga + k0 + 16 * 1024, la + 16 * 32);
        gld16(gb + k0, lb);
        gld16(gb + k0 + 16 * 1024, lb + 16 * 32);
        __syncthreads();
        bf16x8 af[4], bfr[4];
#pragma unroll
        for (int mi = 0; mi < 4; ++mi)
            af[mi] = ldfrag(&As[(wm * 64 + mi * 16 + l16) * 32 + quad * 8]);
#pragma unroll
        for (int ni = 0; ni < 4; ++ni)
            bfr[ni] = ldfrag(&Bs[(wn * 64 + ni * 16 + l16) * 32 + quad * 8]);
#pragma unroll
        for (int mi = 0; mi < 4; ++mi)
#pragma unroll
            for (int ni = 0; ni < 4; ++ni)
                acc[mi][ni] = MFMA(af[mi], bfr[ni], acc[mi][ni]);
    }

#pragma unroll
    for (int mi = 0; mi < 4; ++mi)
#pragma unroll
        for (int ni = 0; ni < 4; ++ni)
#pragma unroll
            for (int r = 0; r < 4; ++r) {
                int row = bm * 128 + wm * 64 + mi * 16 + quad * 4 + r;  // flat b*s
                int col = bn * 128 + wn * 64 + ni * 16 + l16;           // h*64+k
                float v = acc[mi][ni][r] + bias[col];
                if (z == 0) v *= QSCALE;
                int b = row >> 11, s = row & 2047;
                int h = col >> 6, k = col & 63;
                unsigned short o = f2bf(v);
                if (z == 2) {
                    Vt[(size_t)((b * 16 + h) * 64 + k) * 2048 + s] = o;
                } else {
                    O[(size_t)((b * 16 + h) * 2048 + s) * 64 + k] = o;
                }
            }
}

// ---------------------------------------------------------------------------
// Column softmax denominators + V scaling fused, double-buffered Q staging:
//   Dcol[s] = sum_q exp2(S[q,s]); then Vt[bh,k,s-range] *= 1/Dcol[s].
// 1 barrier per q-tile; gld16 prefetch overlaps MFMA+exp body.
// ---------------------------------------------------------------------------
__global__ __launch_bounds__(256) void colsum_vscale(
        const unsigned short* __restrict__ Qh, const unsigned short* __restrict__ Kh,
        unsigned short* __restrict__ Vt) {
    const int tid = threadIdx.x;
    const int st = blockIdx.x, bh = blockIdx.y;
    const unsigned short* Qb = Qh + (size_t)bh * 2048 * 64;
    const unsigned short* Kb = Kh + (size_t)bh * 2048 * 64;

    __shared__ __align__(16) unsigned short Qs[2][2][128 * 32];  // [buf][ks][row*32]
    __shared__ float Dtmp[2][128];
    __shared__ float Dsh[128];

    const int lane = tid & 63, wid = tid >> 6;
    const int l16 = lane & 15, quad = lane >> 4;
    const int wm = wid & 1, wn = wid >> 1;

    // K B-frags for this wave's 64 s-columns, register resident
    bf16x8 kf[2][4];
#pragma unroll
    for (int ks = 0; ks < 2; ++ks)
#pragma unroll
        for (int ni = 0; ni < 4; ++ni)
            kf[ks][ni] = ldfrag(&Kb[(size_t)(st * 128 + wn * 64 + ni * 16 + l16) * 64 +
                                    ks * 32 + quad * 8]);

    const unsigned short* gq =
        Qb + (size_t)(wid * 32 + (lane >> 2)) * 64 + (lane & 3) * 8;

    // prologue: stage tile 0 into buf 0
#pragma unroll
    for (int ks = 0; ks < 2; ++ks) {
        gld16(gq + ks * 32, &Qs[0][ks][wid * 32 * 32]);
        gld16(gq + (size_t)16 * 64 + ks * 32, &Qs[0][ks][(wid * 32 + 16) * 32]);
    }

    float psum[4] = {0.f, 0.f, 0.f, 0.f};
    for (int it = 0; it < 16; ++it) {
        const int buf = it & 1;
        __syncthreads();   // tile `it` staged (vmcnt drain); buf^1 reads done
        if (it < 15) {
            const size_t q1 = (size_t)(it + 1) * 128;
#pragma unroll
            for (int ks = 0; ks < 2; ++ks) {
                gld16(gq + q1 * 64 + ks * 32, &Qs[buf ^ 1][ks][wid * 32 * 32]);
                gld16(gq + (q1 + 16) * 64 + ks * 32,
                      &Qs[buf ^ 1][ks][(wid * 32 + 16) * 32]);
            }
        }
        f32x4 acc[4][4] = {};
#pragma unroll
        for (int ks = 0; ks < 2; ++ks) {
            bf16x8 af[4];
#pragma unroll
            for (int mi = 0; mi < 4; ++mi)
                af[mi] = ldfrag(&Qs[buf][ks][(wm * 64 + mi * 16 + l16) * 32 + quad * 8]);
#pragma unroll
            for (int mi = 0; mi < 4; ++mi)
#pragma unroll
                for (int ni = 0; ni < 4; ++ni)
                    acc[mi][ni] = MFMA(af[mi], kf[ks][ni], acc[mi][ni]);
        }
#pragma unroll
        for (int ni = 0; ni < 4; ++ni) {
            float d = 0.f;
#pragma unroll
            for (int mi = 0; mi < 4; ++mi)
#pragma unroll
                for (int r = 0; r < 4; ++r)
                    d += fast_exp2(acc[mi][ni][r]);
            psum[ni] += d;
        }
    }
#pragma unroll
    for (int ni = 0; ni < 4; ++ni) {           // reduce over quad groups (rows)
        float v = psum[ni];
        v += __shfl_xor(v, 16, 64);
        v += __shfl_xor(v, 32, 64);
        if (quad == 0) Dtmp[wm][wn * 64 + ni * 16 + l16] = v;
    }
    __syncthreads();
    if (tid < 128) Dsh[tid] = 1.0f / (Dtmp[0][tid] + Dtmp[1][tid]);
    __syncthreads();

    // scale V in place: rows k=tid>>2 (64), s-chunk c=tid&3 (32 each)
    const int k = tid >> 2, c = tid & 3;
    unsigned short* vrow = Vt + ((size_t)bh * 64 + k) * 2048 + st * 128 + c * 32;
#pragma unroll
    for (int j = 0; j < 4; ++j) {
        bf16x8 v = *(const bf16x8*)&vrow[j * 8];
        bf16x8 o;
#pragma unroll
        for (int e = 0; e < 8; ++e)
            o[e] = (__bf16)((float)v[e] * Dsh[c * 32 + j * 8 + e]);
        *(bf16x8*)&vrow[j * 8] = o;
    }
}

// ---------------------------------------------------------------------------
// attn*V, software-pipelined across tiles:
//   segment i: [prefetch K(i+1), V(i)] ; phase1(i): S^T=K.Q^T, exp2 -> Ps[i&1]
//              phase2(i-1): ctx^T += V^T.P^T from Ps[(i-1)&1]
// One barrier per segment. Ks/Vs/Ps all double-buffered.
// Waves 0,1 stage K halves; waves 2,3 stage V halves (gld16).
// ---------------------------------------------------------------------------
__global__ __launch_bounds__(256) void attnpv(const unsigned short* __restrict__ Qh,
                                              const unsigned short* __restrict__ Kh,
                                              const unsigned short* __restrict__ Vn,
                                              unsigned short* __restrict__ Ctx) {
    const int tid = threadIdx.x;
    const int qt = blockIdx.x, bh = blockIdx.y;
    const int b = bh >> 4, h = bh & 15;
    const unsigned short* Qb = Qh + (size_t)bh * 2048 * 64;
    const unsigned short* Kb = Kh + (size_t)bh * 2048 * 64;
    const unsigned short* Vb = Vn + (size_t)bh * 64 * 2048;

    __shared__ __align__(16) unsigned short Ks[2][2][64 * 32];  // [buf][khalf][s*32]
    __shared__ __align__(16) unsigned short Vs[2][2][64 * 32];  // [buf][shalf][k*32]
    __shared__ __align__(16) unsigned short Ps[2][128 * 72];    // [buf][q][s^swz]

    const int lane = tid & 63, wid = tid >> 6;
    const int l16 = lane & 15, quad = lane >> 4;
    const int wq = wid & 1, ws = wid >> 1;
    const int swz = (l16 & 3) << 3;        // Ps column swizzle (16B-preserving)

    // Q B-frags for this wave's 64 q columns, register resident
    bf16x8 qf[2][4];
#pragma unroll
    for (int ks = 0; ks < 2; ++ks)
#pragma unroll
        for (int nj = 0; nj < 4; ++nj)
            qf[ks][nj] = ldfrag(&Qb[(size_t)(qt * 128 + wq * 64 + nj * 16 + l16) * 64 +
                                    ks * 32 + quad * 8]);

    // staging role: wid 0,1 -> K half wid; wid 2,3 -> V half wid-2
    const int srow = lane >> 2, scol = (lane & 3) * 8, half = wid & 1;
    const unsigned short* gk = Kb + (size_t)srow * 64 + half * 32 + scol;
    const unsigned short* gv = Vb + (size_t)srow * 2048 + half * 32 + scol;

    // prologue: stage K tile 0 into buf 0 (K waves only)
    if (wid < 2) {
#pragma unroll
        for (int gi = 0; gi < 4; ++gi)
            gld16(gk + (size_t)gi * 16 * 64, &Ks[0][half][gi * 16 * 32]);
    }

    f32x4 cacc[2][4] = {};
    for (int it = 0; it < 32; ++it) {
        const int pb = it & 1;
        __syncthreads();   // K(it), V(it-1) staged; prior-buf LDS reads done

        // prefetch: K tile it+1 -> buf pb^1 ; V tile it -> buf pb
        if (wid < 2) {
            if (it < 31) {
                const size_t s1 = (size_t)(it + 1) * 64;
#pragma unroll
                for (int gi = 0; gi < 4; ++gi)
                    gld16(gk + (s1 + gi * 16) * 64, &Ks[pb ^ 1][half][gi * 16 * 32]);
            }
        } else {
#pragma unroll
            for (int gi = 0; gi < 4; ++gi)
                gld16(gv + (size_t)(gi * 16) * 2048 + it * 64,
                      &Vs[pb][half][gi * 16 * 32]);
        }

        // phase 1 (tile it): S^T (64s x 128q), this wave: 32 s x 64 q
        bf16x8 kf[2][2];
#pragma unroll
        for (int mi = 0; mi < 2; ++mi)
#pragma unroll
            for (int ks = 0; ks < 2; ++ks)
                kf[mi][ks] = ldfrag(&Ks[pb][ks][(ws * 32 + mi * 16 + l16) * 32 + quad * 8]);
        f32x4 sacc[2][4] = {};
#pragma unroll
        for (int ks = 0; ks < 2; ++ks)
#pragma unroll
            for (int mi = 0; mi < 2; ++mi)
#pragma unroll
                for (int nj = 0; nj < 4; ++nj)
                    sacc[mi][nj] = MFMA(kf[mi][ks], qf[ks][nj], sacc[mi][nj]);

        // phase 2 (tile it-1) LDS reads -- independent of phase-1's exp chain
        bf16x8 vf[2][2], pf2[2][4];
        if (it > 0) {
#pragma unroll
            for (int mi = 0; mi < 2; ++mi)
#pragma unroll
                for (int ks2 = 0; ks2 < 2; ++ks2)
                    vf[mi][ks2] =
                        ldfrag(&Vs[pb ^ 1][ks2][(ws * 32 + mi * 16 + l16) * 32 + quad * 8]);
#pragma unroll
            for (int ks2 = 0; ks2 < 2; ++ks2)
#pragma unroll
                for (int nj = 0; nj < 4; ++nj)
                    pf2[ks2][nj] = ldfrag(&Ps[pb ^ 1][(size_t)(wq * 64 + nj * 16 + l16) * 72 +
                                              ((ks2 * 32 + quad * 8) ^ swz)]);
        }

        // exp2 + packed Ps write (4 consecutive s per lane -> b64, swizzled)
#pragma unroll
        for (int mi = 0; mi < 2; ++mi)
#pragma unroll
            for (int nj = 0; nj < 4; ++nj) {
                ushort4 p;
                p.x = f2bf(fast_exp2(sacc[mi][nj][0]));
                p.y = f2bf(fast_exp2(sacc[mi][nj][1]));
                p.z = f2bf(fast_exp2(sacc[mi][nj][2]));
                p.w = f2bf(fast_exp2(sacc[mi][nj][3]));
                *(ushort4*)&Ps[pb][(size_t)(wq * 64 + nj * 16 + l16) * 72 +
                                   ((ws * 32 + mi * 16 + quad * 4) ^ swz)] = p;
            }

        // phase 2 (tile it-1) MFMA
        if (it > 0) {
#pragma unroll
            for (int ks2 = 0; ks2 < 2; ++ks2)
#pragma unroll
                for (int mi = 0; mi < 2; ++mi)
#pragma unroll
                    for (int nj = 0; nj < 4; ++nj)
                        cacc[mi][nj] = MFMA(vf[mi][ks2], pf2[ks2][nj], cacc[mi][nj]);
        }
    }

    // epilogue: phase 2 for tile 31 (Ps[1], Vs[1])
    __syncthreads();
    {
        bf16x8 vf[2][2], pf2[2][4];
#pragma unroll
        for (int mi = 0; mi < 2; ++mi)
#pragma unroll
            for (int ks2 = 0; ks2 < 2; ++ks2)
                vf[mi][ks2] = ldfrag(&Vs[1][ks2][(ws * 32 + mi * 16 + l16) * 32 + quad * 8]);
#pragma unroll
        for (int ks2 = 0; ks2 < 2; ++ks2)
#pragma unroll
            for (int nj = 0; nj < 4; ++nj)
                pf2[ks2][nj] = ldfrag(&Ps[1][(size_t)(wq * 64 + nj * 16 + l16) * 72 +
                                          ((ks2 * 32 + quad * 8) ^ swz)]);
#pragma unroll
        for (int ks2 = 0; ks2 < 2; ++ks2)
#pragma unroll
            for (int mi = 0; mi < 2; ++mi)
#pragma unroll
                for (int nj = 0; nj < 4; ++nj)
                    cacc[mi][nj] = MFMA(vf[mi][ks2], pf2[ks2][nj], cacc[mi][nj]);
    }

    // epilogue store: cacc row = k (quad*4+r), col = q (l16); 4 k -> b64
#pragma unroll
    for (int mi = 0; mi < 2; ++mi)
#pragma unroll
        for (int nj = 0; nj < 4; ++nj) {
            int q = qt * 128 + wq * 64 + nj * 16 + l16;
            int k = ws * 32 + mi * 16 + quad * 4;
            ushort4 o;
            o.x = f2bf(cacc[mi][nj][0]);
            o.y = f2bf(cacc[mi][nj][1]);
            o.z = f2bf(cacc[mi][nj][2]);
            o.w = f2bf(cacc[mi][nj][3]);
            *(ushort4*)&Ctx[(size_t)(b * 2048 + q) * 1024 + h * 64 + k] = o;
        }
}

// ---------------------------------------------------------------------------
// Output GEMM (m97-style): Out[8192x1024] f32 = Ctx(bf16) * Wo^T + bo
// ---------------------------------------------------------------------------
__global__ __launch_bounds__(256) void out_gemm(const unsigned short* __restrict__ A,
                                                const unsigned short* __restrict__ Bt,
                                                const float* __restrict__ bias,
                                                float* __restrict__ Out) {
    const int tid = threadIdx.x;
    const int bm = blockIdx.x, bn = blockIdx.y;

    __shared__ __align__(16) unsigned short As[128 * 32];
    __shared__ __align__(16) unsigned short Bs[128 * 32];

    const int lane = tid & 63, wid = tid >> 6;
    const int l16 = lane & 15, quad = lane >> 4;
    const int wm = wid & 1, wn = wid >> 1;

    const unsigned short* ga =
        A + (size_t)(bm * 128 + wid * 32 + (lane >> 2)) * 1024 + (lane & 3) * 8;
    const unsigned short* gb =
        Bt + (size_t)(bn * 128 + wid * 32 + (lane >> 2)) * 1024 + (lane & 3) * 8;
    unsigned short* la = &As[wid * 32 * 32];
    unsigned short* lb = &Bs[wid * 32 * 32];

    f32x4 acc[4][4] = {};
    for (int kt = 0; kt < 32; ++kt) {
        __syncthreads();
        const int k0 = kt * 32;
        gld16(ga + k0, la);
        gld16(ga + k0 + 16 * 1024, la + 16 * 32);
        gld16(gb + k0, lb);
        gld16(gb + k0 + 16 * 1024, lb + 16 * 32);
        __syncthreads();
        bf16x8 af[4], bfr[4];
#pragma unroll
        for (int mi = 0; mi < 4; ++mi)
            af[mi] = ldfrag(&As[(wm * 64 + mi * 16 + l16) * 32 + quad * 8]);
#pragma unroll
        for (int ni = 0; ni < 4; ++ni)
            bfr[ni] = ldfrag(&Bs[(wn * 64 + ni * 16 + l16) * 32 + quad * 8]);
#pragma unroll
        for (int mi = 0; mi < 4; ++mi)
#pragma unroll
            for (int ni = 0; ni < 4; ++ni)
                acc[mi][ni] = MFMA(af[mi], bfr[ni], acc[mi][ni]);
    }
#pragma unroll
    for (int mi = 0; mi < 4; ++mi)
#pragma unroll
        for (int ni = 0; ni < 4; ++ni)
#pragma unroll
            for (int r = 0; r < 4; ++r) {
                int row = bm * 128 + wm * 64 + mi * 16 + quad * 4 + r;
                int col = bn * 128 + wn * 64 + ni * 16 + l16;
                Out[(size_t)row * 1024 + col] = acc[mi][ni][r] + bias[col];
            }
}

// ---------------------------------------------------------------------------
extern "C" void kernel_launch(void* const* d_in, const int* in_sizes, int n_in,
                              void* d_out, int out_size, void* d_ws, size_t ws_size,
                              hipStream_t stream) {
    (void)in_sizes; (void)n_in; (void)out_size; (void)ws_size;
    const float* X[3] = {(const float*)d_in[0], (const float*)d_in[1],
                         (const float*)d_in[2]};
    const float* Wq = (const float*)d_in[3];
    const float* bq = (const float*)d_in[4];
    const float* Wk = (const float*)d_in[5];
    const float* bk = (const float*)d_in[6];
    const float* Wv = (const float*)d_in[7];
    const float* bv = (const float*)d_in[8];
    const float* Wo = (const float*)d_in[9];
    const float* bo = (const float*)d_in[10];
    const float* bias[3] = {bq, bk, bv};
    float* Out = (float*)d_out;

    char* ws = (char*)d_ws;
    const size_t MB = 1024 * 1024;
    unsigned short* Wt  = (unsigned short*)(ws);            // 6 MB  [3][1024][1024] bf16
    unsigned short* Wot = (unsigned short*)(ws + 6 * MB);   // 2 MB
    unsigned short* Qh  = (unsigned short*)(ws + 8 * MB);   // 16 MB [b,h,s,64] (pre-scaled)
    unsigned short* Kh  = (unsigned short*)(ws + 24 * MB);  // 16 MB
    unsigned short* Vt  = (unsigned short*)(ws + 40 * MB);  // 16 MB [b,h,64,s] -> scaled in place
    unsigned short* Ctx = (unsigned short*)(ws + 56 * MB);  // 16 MB [b*s,1024]
    unsigned short* Xb  = Ctx;                              // alias: Xb dead before Ctx live
    unsigned short* Oz[3] = {Qh, Kh, Qh /*unused for z=2*/};

    wprep<<<dim3(4096, 4), dim3(256), 0, stream>>>(Wq, Wk, Wv, Wo, Wt, Wot);
    for (int z = 0; z < 3; ++z) {
        xprep<<<dim3(8192), dim3(256), 0, stream>>>(X[z], Xb);
        proj_gemm<<<dim3(64, 8), dim3(256), 0, stream>>>(
            Xb, Wt + (size_t)z * 1048576, bias[z], Oz[z], Vt, z);
    }
    colsum_vscale<<<dim3(16, 64), dim3(256), 0, stream>>>(Qh, Kh, Vt);
    attnpv<<<dim3(16, 64), dim3(256), 0, stream>>>(Qh, Kh, Vt, Ctx);
    out_gemm<<<dim3(64, 8), dim3(256), 0, stream>>>(Ctx, Wot, bo, Out);
}

// Round 7
// 440.824 us; speedup vs baseline: 1.2378x; 1.0300x over previous
//
#include <hip/hip_runtime.h>

// MultiHeadedAttention: B=4, S=2048, H=16, D_MODEL=1024, D_K=64
// Softmax over the QUERY axis (per key-column normalization).
// Pipeline: wprep -> 3x(xprep, proj_gemm) -> colsum_vscale -> attnpv -> out_gemm
// R7: attnpv s-split phase2 -> P is fully intra-wave (no cross-wave P, no
//     P barrier), conflict-free granule-XOR P layout, LDS 48KB (3 blocks/CU),
//     LDS bytes/iter 96->80KB with ~zero conflicts; final cross-wave cacc
//     reduce through LDS scratch aliasing Ks/Vs.

#define DEV __device__ __forceinline__

typedef __bf16 bf16x8 __attribute__((ext_vector_type(8)));
typedef float  f32x4  __attribute__((ext_vector_type(4)));

DEV unsigned short f2bf(float f) {
    __bf16 h = (__bf16)f;
    return __builtin_bit_cast(unsigned short, h);
}

DEV bf16x8 ldfrag(const unsigned short* p) {
    return *reinterpret_cast<const bf16x8*>(p);
}

DEV float fast_exp2(float x) {
#if __has_builtin(__builtin_amdgcn_exp2f)
    return __builtin_amdgcn_exp2f(x);
#else
    return exp2f(x);
#endif
}

// async global->LDS, 16B per lane; LDS dst = wave-uniform base + lane*16
DEV void gld16(const unsigned short* g, unsigned short* l) {
    __builtin_amdgcn_global_load_lds(
        (__attribute__((address_space(1))) void*)g,
        (__attribute__((address_space(3))) void*)l, 16, 0, 0);
}

#define MFMA(a,b,c) __builtin_amdgcn_mfma_f32_16x16x32_bf16((a),(b),(c),0,0,0)

// score*1/sqrt(64) then exp -> exp2(score * log2(e)/8); folded into Qh.
#define QSCALE 0.18033688011112042f

// ---------------------------------------------------------------------------
// Weight prep: Wq/Wk/Wv [16,1024,64] f32 -> Wt[z][n=h*64+k][m] bf16 (B^T layout)
//              Wo [1024,1024] f32 -> bf16 (already [n][m])
// ---------------------------------------------------------------------------
__global__ __launch_bounds__(256) void wprep(const float* __restrict__ Wq,
                                             const float* __restrict__ Wk,
                                             const float* __restrict__ Wv,
                                             const float* __restrict__ Wo,
                                             unsigned short* __restrict__ Wt,
                                             unsigned short* __restrict__ Wot) {
    int idx = blockIdx.x * 256 + threadIdx.x;   // < 1024*1024
    int which = blockIdx.y;
    if (which == 3) { Wot[idx] = f2bf(Wo[idx]); return; }
    const float* W = (which == 0) ? Wq : (which == 1) ? Wk : Wv;
    int n = idx >> 10, m = idx & 1023;
    int h = n >> 6, k = n & 63;
    Wt[(size_t)which * 1048576 + idx] = f2bf(W[h * 65536 + m * 64 + k]);
}

// ---------------------------------------------------------------------------
// X f32 -> bf16 (one input of 8192x1024 per launch)
// ---------------------------------------------------------------------------
__global__ __launch_bounds__(256) void xprep(const float* __restrict__ X,
                                             unsigned short* __restrict__ Xb) {
    int idx = (blockIdx.x * 256 + threadIdx.x) * 4;
    float4 f = *(const float4*)&X[idx];
    ushort4 o;
    o.x = f2bf(f.x); o.y = f2bf(f.y); o.z = f2bf(f.z); o.w = f2bf(f.w);
    *(ushort4*)&Xb[idx] = o;
}

// ---------------------------------------------------------------------------
// Projection GEMM (m97-style): C[8192x1024] = Xb * Bt^T + bias
// z=0 -> O=Qh[b,h,s,k] (pre-scaled by QSCALE); z=1 -> O=Kh; z=2 -> Vt[b,h,k,s]
// ---------------------------------------------------------------------------
__global__ __launch_bounds__(256) void proj_gemm(
        const unsigned short* __restrict__ Xb, const unsigned short* __restrict__ Bt,
        const float* __restrict__ bias, unsigned short* __restrict__ O,
        unsigned short* __restrict__ Vt, int z) {
    const int tid = threadIdx.x;
    const int bm = blockIdx.x, bn = blockIdx.y;

    __shared__ __align__(16) unsigned short As[128 * 32];
    __shared__ __align__(16) unsigned short Bs[128 * 32];

    const int lane = tid & 63, wid = tid >> 6;
    const int l16 = lane & 15, quad = lane >> 4;
    const int wm = wid & 1, wn = wid >> 1;

    const unsigned short* ga =
        Xb + (size_t)(bm * 128 + wid * 32 + (lane >> 2)) * 1024 + (lane & 3) * 8;
    const unsigned short* gb =
        Bt + (size_t)(bn * 128 + wid * 32 + (lane >> 2)) * 1024 + (lane & 3) * 8;
    unsigned short* la = &As[wid * 32 * 32];
    unsigned short* lb = &Bs[wid * 32 * 32];

    f32x4 acc[4][4] = {};
    for (int kt = 0; kt < 32; ++kt) {
        __syncthreads();
        const int k0 = kt * 32;
        gld16(ga + k0, la);
        gld16(ga + k0 + 16 * 1024, la + 16 * 32);
        gld16(gb + k0, lb);
        gld16(gb + k0 + 16 * 1024, lb + 16 * 32);
        __syncthreads();
        bf16x8 af[4], bfr[4];
#pragma unroll
        for (int mi = 0; mi < 4; ++mi)
            af[mi] = ldfrag(&As[(wm * 64 + mi * 16 + l16) * 32 + quad * 8]);
#pragma unroll
        for (int ni = 0; ni < 4; ++ni)
            bfr[ni] = ldfrag(&Bs[(wn * 64 + ni * 16 + l16) * 32 + quad * 8]);
#pragma unroll
        for (int mi = 0; mi < 4; ++mi)
#pragma unroll
            for (int ni = 0; ni < 4; ++ni)
                acc[mi][ni] = MFMA(af[mi], bfr[ni], acc[mi][ni]);
    }

#pragma unroll
    for (int mi = 0; mi < 4; ++mi)
#pragma unroll
        for (int ni = 0; ni < 4; ++ni)
#pragma unroll
            for (int r = 0; r < 4; ++r) {
                int row = bm * 128 + wm * 64 + mi * 16 + quad * 4 + r;  // flat b*s
                int col = bn * 128 + wn * 64 + ni * 16 + l16;           // h*64+k
                float v = acc[mi][ni][r] + bias[col];
                if (z == 0) v *= QSCALE;
                int b = row >> 11, s = row & 2047;
                int h = col >> 6, k = col & 63;
                unsigned short o = f2bf(v);
                if (z == 2) {
                    Vt[(size_t)((b * 16 + h) * 64 + k) * 2048 + s] = o;
                } else {
                    O[(size_t)((b * 16 + h) * 2048 + s) * 64 + k] = o;
                }
            }
}

// ---------------------------------------------------------------------------
// Column softmax denominators + V scaling fused, double-buffered Q staging:
//   Dcol[s] = sum_q exp2(S[q,s]); then Vt[bh,k,s-range] *= 1/Dcol[s].
// ---------------------------------------------------------------------------
__global__ __launch_bounds__(256) void colsum_vscale(
        const unsigned short* __restrict__ Qh, const unsigned short* __restrict__ Kh,
        unsigned short* __restrict__ Vt) {
    const int tid = threadIdx.x;
    const int st = blockIdx.x, bh = blockIdx.y;
    const unsigned short* Qb = Qh + (size_t)bh * 2048 * 64;
    const unsigned short* Kb = Kh + (size_t)bh * 2048 * 64;

    __shared__ __align__(16) unsigned short Qs[2][2][128 * 32];  // [buf][ks][row*32]
    __shared__ float Dtmp[2][128];
    __shared__ float Dsh[128];

    const int lane = tid & 63, wid = tid >> 6;
    const int l16 = lane & 15, quad = lane >> 4;
    const int wm = wid & 1, wn = wid >> 1;

    // K B-frags for this wave's 64 s-columns, register resident
    bf16x8 kf[2][4];
#pragma unroll
    for (int ks = 0; ks < 2; ++ks)
#pragma unroll
        for (int ni = 0; ni < 4; ++ni)
            kf[ks][ni] = ldfrag(&Kb[(size_t)(st * 128 + wn * 64 + ni * 16 + l16) * 64 +
                                    ks * 32 + quad * 8]);

    const unsigned short* gq =
        Qb + (size_t)(wid * 32 + (lane >> 2)) * 64 + (lane & 3) * 8;

    // prologue: stage tile 0 into buf 0
#pragma unroll
    for (int ks = 0; ks < 2; ++ks) {
        gld16(gq + ks * 32, &Qs[0][ks][wid * 32 * 32]);
        gld16(gq + (size_t)16 * 64 + ks * 32, &Qs[0][ks][(wid * 32 + 16) * 32]);
    }

    float psum[4] = {0.f, 0.f, 0.f, 0.f};
    for (int it = 0; it < 16; ++it) {
        const int buf = it & 1;
        __syncthreads();   // tile `it` staged (vmcnt drain); buf^1 reads done
        if (it < 15) {
            const size_t q1 = (size_t)(it + 1) * 128;
#pragma unroll
            for (int ks = 0; ks < 2; ++ks) {
                gld16(gq + q1 * 64 + ks * 32, &Qs[buf ^ 1][ks][wid * 32 * 32]);
                gld16(gq + (q1 + 16) * 64 + ks * 32,
                      &Qs[buf ^ 1][ks][(wid * 32 + 16) * 32]);
            }
        }
        f32x4 acc[4][4] = {};
#pragma unroll
        for (int ks = 0; ks < 2; ++ks) {
            bf16x8 af[4];
#pragma unroll
            for (int mi = 0; mi < 4; ++mi)
                af[mi] = ldfrag(&Qs[buf][ks][(wm * 64 + mi * 16 + l16) * 32 + quad * 8]);
#pragma unroll
            for (int mi = 0; mi < 4; ++mi)
#pragma unroll
                for (int ni = 0; ni < 4; ++ni)
                    acc[mi][ni] = MFMA(af[mi], kf[ks][ni], acc[mi][ni]);
        }
#pragma unroll
        for (int ni = 0; ni < 4; ++ni) {
            float d = 0.f;
#pragma unroll
            for (int mi = 0; mi < 4; ++mi)
#pragma unroll
                for (int r = 0; r < 4; ++r)
                    d += fast_exp2(acc[mi][ni][r]);
            psum[ni] += d;
        }
    }
#pragma unroll
    for (int ni = 0; ni < 4; ++ni) {           // reduce over quad groups (rows)
        float v = psum[ni];
        v += __shfl_xor(v, 16, 64);
        v += __shfl_xor(v, 32, 64);
        if (quad == 0) Dtmp[wm][wn * 64 + ni * 16 + l16] = v;
    }
    __syncthreads();
    if (tid < 128) Dsh[tid] = 1.0f / (Dtmp[0][tid] + Dtmp[1][tid]);
    __syncthreads();

    // scale V in place: rows k=tid>>2 (64), s-chunk c=tid&3 (32 each)
    const int k = tid >> 2, c = tid & 3;
    unsigned short* vrow = Vt + ((size_t)bh * 64 + k) * 2048 + st * 128 + c * 32;
#pragma unroll
    for (int j = 0; j < 4; ++j) {
        bf16x8 v = *(const bf16x8*)&vrow[j * 8];
        bf16x8 o;
#pragma unroll
        for (int e = 0; e < 8; ++e)
            o[e] = (__bf16)((float)v[e] * Dsh[c * 32 + j * 8 + e]);
        *(bf16x8*)&vrow[j * 8] = o;
    }
}

// ---------------------------------------------------------------------------
// attn*V, s-split phase2 (P fully intra-wave):
//   wave (wq, ws): phase1: S^T[s in ws-half32][q in wq-half64] = K.Q^T
//                  exp2 -> per-wave P LDS region (granule-XOR, conflict-free)
//                  phase2: partial ctx^T[k all 64][q 64] over own s-half
//   1 barrier/iter (K/V dbuf staging only). Final cacc reduce (ws pairs)
//   through 32KB scratch aliasing Ks/Vs.
// ---------------------------------------------------------------------------
__global__ __launch_bounds__(256) void attnpv(const unsigned short* __restrict__ Qh,
                                              const unsigned short* __restrict__ Kh,
                                              const unsigned short* __restrict__ Vn,
                                              unsigned short* __restrict__ Ctx) {
    const int tid = threadIdx.x;
    const int qt = blockIdx.x, bh = blockIdx.y;
    const int b = bh >> 4, h = bh & 15;
    const unsigned short* Qb = Qh + (size_t)bh * 2048 * 64;
    const unsigned short* Kb = Kh + (size_t)bh * 2048 * 64;
    const unsigned short* Vb = Vn + (size_t)bh * 64 * 2048;

    __shared__ __align__(16) unsigned char smem[49152];
    unsigned short* Ks = (unsigned short*)smem;             // [buf2][khalf2][64*32]
    unsigned short* Vs = (unsigned short*)(smem + 16384);   // [buf2][shalf2][64*32]
    unsigned short* Pw = (unsigned short*)(smem + 32768) + (tid >> 6) * 2048;
    // Pw: per-wave [q 64][s 32], rows 64B, 8-elem granules XOR'd by (q&3)

    const int lane = tid & 63, wid = tid >> 6;
    const int l16 = lane & 15, quad = lane >> 4;
    const int wq = wid & 1, ws = wid >> 1;
    const int pq = l16 & 3;                 // == q&3 for this lane's P rows

    // Q B-frags for this wave's 64 q columns, register resident
    bf16x8 qf[2][4];
#pragma unroll
    for (int ks = 0; ks < 2; ++ks)
#pragma unroll
        for (int nj = 0; nj < 4; ++nj)
            qf[ks][nj] = ldfrag(&Qb[(size_t)(qt * 128 + wq * 64 + nj * 16 + l16) * 64 +
                                    ks * 32 + quad * 8]);

    // staging role: wid 0,1 -> K half wid; wid 2,3 -> V half wid-2
    const int srow = lane >> 2, scol = (lane & 3) * 8, half = wid & 1;
    const unsigned short* gk = Kb + (size_t)srow * 64 + half * 32 + scol;
    const unsigned short* gv = Vb + (size_t)srow * 2048 + half * 32 + scol;

    // prologue: stage K(0), V(0) into buf 0
    if (wid < 2) {
#pragma unroll
        for (int gi = 0; gi < 4; ++gi)
            gld16(gk + (size_t)gi * 16 * 64, &Ks[half * 2048 + gi * 16 * 32]);
    } else {
#pragma unroll
        for (int gi = 0; gi < 4; ++gi)
            gld16(gv + (size_t)gi * 16 * 2048, &Vs[half * 2048 + gi * 16 * 32]);
    }

    f32x4 cacc[4][4] = {};
    for (int it = 0; it < 32; ++it) {
        const int pb = it & 1;
        __syncthreads();   // K(it),V(it) staged in pb; pb^1 reads of it-1 done

        // prefetch K(it+1), V(it+1) into buf pb^1 (overlaps whole body)
        if (it < 31) {
            const size_t s1 = (size_t)(it + 1) * 64;
            if (wid < 2) {
#pragma unroll
                for (int gi = 0; gi < 4; ++gi)
                    gld16(gk + (s1 + gi * 16) * 64,
                          &Ks[((pb ^ 1) * 2 + half) * 2048 + gi * 16 * 32]);
            } else {
#pragma unroll
                for (int gi = 0; gi < 4; ++gi)
                    gld16(gv + (size_t)(gi * 16) * 2048 + s1,
                          &Vs[((pb ^ 1) * 2 + half) * 2048 + gi * 16 * 32]);
            }
        }

        // phase 1: S^T (this wave: s = ws*32+[0,32), q = wq*64+[0,64))
        bf16x8 kf[2][2];
#pragma unroll
        for (int mi = 0; mi < 2; ++mi)
#pragma unroll
            for (int ks = 0; ks < 2; ++ks)
                kf[mi][ks] = ldfrag(&Ks[(pb * 2 + ks) * 2048 +
                                        (ws * 32 + mi * 16 + l16) * 32 + quad * 8]);
        f32x4 sacc[2][4] = {};
#pragma unroll
        for (int ks = 0; ks < 2; ++ks)
#pragma unroll
            for (int mi = 0; mi < 2; ++mi)
#pragma unroll
                for (int nj = 0; nj < 4; ++nj)
                    sacc[mi][nj] = MFMA(kf[mi][ks], qf[ks][nj], sacc[mi][nj]);

        // exp2 -> P write (b64, granule-XOR layout; intra-wave only)
#pragma unroll
        for (int mi = 0; mi < 2; ++mi) {
            const int gsw = ((mi * 2 + (quad >> 1)) ^ pq) * 8 + (quad & 1) * 4;
#pragma unroll
            for (int nj = 0; nj < 4; ++nj) {
                ushort4 p;
                p.x = f2bf(fast_exp2(sacc[mi][nj][0]));
                p.y = f2bf(fast_exp2(sacc[mi][nj][1]));
                p.z = f2bf(fast_exp2(sacc[mi][nj][2]));
                p.w = f2bf(fast_exp2(sacc[mi][nj][3]));
                *(ushort4*)&Pw[(nj * 16 + l16) * 32 + gsw] = p;
            }
        }

        // phase 2: partial ctx^T (k all 64, q 64, s = own ws-half)
        bf16x8 vf[4], pf[4];
#pragma unroll
        for (int mi = 0; mi < 4; ++mi)
            vf[mi] = ldfrag(&Vs[(pb * 2 + ws) * 2048 + (mi * 16 + l16) * 32 + quad * 8]);
#pragma unroll
        for (int nj = 0; nj < 4; ++nj)
            pf[nj] = ldfrag(&Pw[(nj * 16 + l16) * 32 + (quad ^ pq) * 8]);
#pragma unroll
        for (int mi = 0; mi < 4; ++mi)
#pragma unroll
            for (int nj = 0; nj < 4; ++nj)
                cacc[mi][nj] = MFMA(vf[mi], pf[nj], cacc[mi][nj]);
    }

    // cross-wave reduce: cacc(wq, ws=0) += cacc(wq, ws=1), then store
    __syncthreads();
    f32x4* Red = (f32x4*)smem;   // [wq][16][64] = 32KB, aliases Ks/Vs
    if (ws == 1) {
#pragma unroll
        for (int mi = 0; mi < 4; ++mi)
#pragma unroll
            for (int nj = 0; nj < 4; ++nj)
                Red[(wq * 16 + mi * 4 + nj) * 64 + lane] = cacc[mi][nj];
    }
    __syncthreads();
    if (ws == 0) {
#pragma unroll
        for (int mi = 0; mi < 4; ++mi)
#pragma unroll
            for (int nj = 0; nj < 4; ++nj) {
                f32x4 t = Red[(wq * 16 + mi * 4 + nj) * 64 + lane];
                int q = qt * 128 + wq * 64 + nj * 16 + l16;
                int k = mi * 16 + quad * 4;
                ushort4 o;
                o.x = f2bf(cacc[mi][nj][0] + t[0]);
                o.y = f2bf(cacc[mi][nj][1] + t[1]);
                o.z = f2bf(cacc[mi][nj][2] + t[2]);
                o.w = f2bf(cacc[mi][nj][3] + t[3]);
                *(ushort4*)&Ctx[(size_t)(b * 2048 + q) * 1024 + h * 64 + k] = o;
            }
    }
}

// ---------------------------------------------------------------------------
// Output GEMM (m97-style): Out[8192x1024] f32 = Ctx(bf16) * Wo^T + bo
// ---------------------------------------------------------------------------
__global__ __launch_bounds__(256) void out_gemm(const unsigned short* __restrict__ A,
                                                const unsigned short* __restrict__ Bt,
                                                const float* __restrict__ bias,
                                                float* __restrict__ Out) {
    const int tid = threadIdx.x;
    const int bm = blockIdx.x, bn = blockIdx.y;

    __shared__ __align__(16) unsigned short As[128 * 32];
    __shared__ __align__(16) unsigned short Bs[128 * 32];

    const int lane = tid & 63, wid = tid >> 6;
    const int l16 = lane & 15, quad = lane >> 4;
    const int wm = wid & 1, wn = wid >> 1;

    const unsigned short* ga =
        A + (size_t)(bm * 128 + wid * 32 + (lane >> 2)) * 1024 + (lane & 3) * 8;
    const unsigned short* gb =
        Bt + (size_t)(bn * 128 + wid * 32 + (lane >> 2)) * 1024 + (lane & 3) * 8;
    unsigned short* la = &As[wid * 32 * 32];
    unsigned short* lb = &Bs[wid * 32 * 32];

    f32x4 acc[4][4] = {};
    for (int kt = 0; kt < 32; ++kt) {
        __syncthreads();
        const int k0 = kt * 32;
        gld16(ga + k0, la);
        gld16(ga + k0 + 16 * 1024, la + 16 * 32);
        gld16(gb + k0, lb);
        gld16(gb + k0 + 16 * 1024, lb + 16 * 32);
        __syncthreads();
        bf16x8 af[4], bfr[4];
#pragma unroll
        for (int mi = 0; mi < 4; ++mi)
            af[mi] = ldfrag(&As[(wm * 64 + mi * 16 + l16) * 32 + quad * 8]);
#pragma unroll
        for (int ni = 0; ni < 4; ++ni)
            bfr[ni] = ldfrag(&Bs[(wn * 64 + ni * 16 + l16) * 32 + quad * 8]);
#pragma unroll
        for (int mi = 0; mi < 4; ++mi)
#pragma unroll
            for (int ni = 0; ni < 4; ++ni)
                acc[mi][ni] = MFMA(af[mi], bfr[ni], acc[mi][ni]);
    }
#pragma unroll
    for (int mi = 0; mi < 4; ++mi)
#pragma unroll
        for (int ni = 0; ni < 4; ++ni)
#pragma unroll
            for (int r = 0; r < 4; ++r) {
                int row = bm * 128 + wm * 64 + mi * 16 + quad * 4 + r;
                int col = bn * 128 + wn * 64 + ni * 16 + l16;
                Out[(size_t)row * 1024 + col] = acc[mi][ni][r] + bias[col];
            }
}

// ---------------------------------------------------------------------------
extern "C" void kernel_launch(void* const* d_in, const int* in_sizes, int n_in,
                              void* d_out, int out_size, void* d_ws, size_t ws_size,
                              hipStream_t stream) {
    (void)in_sizes; (void)n_in; (void)out_size; (void)ws_size;
    const float* X[3] = {(const float*)d_in[0], (const float*)d_in[1],
                         (const float*)d_in[2]};
    const float* Wq = (const float*)d_in[3];
    const float* bq = (const float*)d_in[4];
    const float* Wk = (const float*)d_in[5];
    const float* bk = (const float*)d_in[6];
    const float* Wv = (const float*)d_in[7];
    const float* bv = (const float*)d_in[8];
    const float* Wo = (const float*)d_in[9];
    const float* bo = (const float*)d_in[10];
    const float* bias[3] = {bq, bk, bv};
    float* Out = (float*)d_out;

    char* ws = (char*)d_ws;
    const size_t MB = 1024 * 1024;
    unsigned short* Wt  = (unsigned short*)(ws);            // 6 MB  [3][1024][1024] bf16
    unsigned short* Wot = (unsigned short*)(ws + 6 * MB);   // 2 MB
    unsigned short* Qh  = (unsigned short*)(ws + 8 * MB);   // 16 MB [b,h,s,64] (pre-scaled)
    unsigned short* Kh  = (unsigned short*)(ws + 24 * MB);  // 16 MB
    unsigned short* Vt  = (unsigned short*)(ws + 40 * MB);  // 16 MB [b,h,64,s] -> scaled in place
    unsigned short* Ctx = (unsigned short*)(ws + 56 * MB);  // 16 MB [b*s,1024]
    unsigned short* Xb  = Ctx;                              // alias: Xb dead before Ctx live
    unsigned short* Oz[3] = {Qh, Kh, Qh /*unused for z=2*/};

    wprep<<<dim3(4096, 4), dim3(256), 0, stream>>>(Wq, Wk, Wv, Wo, Wt, Wot);
    for (int z = 0; z < 3; ++z) {
        xprep<<<dim3(8192), dim3(256), 0, stream>>>(X[z], Xb);
        proj_gemm<<<dim3(64, 8), dim3(256), 0, stream>>>(
            Xb, Wt + (size_t)z * 1048576, bias[z], Oz[z], Vt, z);
    }
    colsum_vscale<<<dim3(16, 64), dim3(256), 0, stream>>>(Qh, Kh, Vt);
    attnpv<<<dim3(16, 64), dim3(256), 0, stream>>>(Qh, Kh, Vt, Ctx);
    out_gemm<<<dim3(64, 8), dim3(256), 0, stream>>>(Ctx, Wot, bo, Out);
}